// Round 1
// baseline (744.569 us; speedup 1.0000x reference)
//
#include <hip/hip_runtime.h>

#define S_LEN 2048
#define NB 4
#define NH 8
#define DKH 12
#define DVH 32

// ---------------------------------------------------------------------------
// Generic tiled fp32 GEMM with bias: C[M,N] = A[M,K] @ B[K,N] + bias[N]
// Block: 256 threads computes a 64x32 tile. K multiple of 16, N multiple of 32,
// M multiple of 64 (all true here: K in {512,256}, N in {96,256,512}, M=8192).
// ---------------------------------------------------------------------------
__global__ __launch_bounds__(256) void gemm_bias_kernel(
    const float* __restrict__ A, const float* __restrict__ Bm,
    const float* __restrict__ bias, float* __restrict__ C,
    int M, int N, int K)
{
  __shared__ float As[16][68];   // [k][row], padded: row-write spread, b128-read aligned (68*4=272, 272%16==0)
  __shared__ float Bs[16][32];   // [k][col]

  const int t  = threadIdx.x;
  const int r0 = blockIdx.x * 64;
  const int c0 = blockIdx.y * 32;
  const int tc = (t & 15) * 2;   // col pair
  const int tr = (t >> 4) * 4;   // row quad

  float acc00 = 0.f, acc01 = 0.f, acc10 = 0.f, acc11 = 0.f;
  float acc20 = 0.f, acc21 = 0.f, acc30 = 0.f, acc31 = 0.f;

  const int arow = t >> 2;        // 0..63
  const int akq  = (t & 3) * 4;   // 0,4,8,12

  for (int k0 = 0; k0 < K; k0 += 16) {
    // stage A tile (transposed into LDS)
    const float4 a4 = *reinterpret_cast<const float4*>(
        A + (size_t)(r0 + arow) * K + k0 + akq);
    As[akq + 0][arow] = a4.x;
    As[akq + 1][arow] = a4.y;
    As[akq + 2][arow] = a4.z;
    As[akq + 3][arow] = a4.w;
    // stage B tile
#pragma unroll
    for (int j = t; j < 512; j += 256) {
      const int kk = j >> 5, cc = j & 31;
      Bs[kk][cc] = Bm[(size_t)(k0 + kk) * N + c0 + cc];
    }
    __syncthreads();
#pragma unroll
    for (int kk = 0; kk < 16; ++kk) {
      const float4 a  = *reinterpret_cast<const float4*>(&As[kk][tr]);
      const float2 bv = *reinterpret_cast<const float2*>(&Bs[kk][tc]);
      acc00 += a.x * bv.x; acc01 += a.x * bv.y;
      acc10 += a.y * bv.x; acc11 += a.y * bv.y;
      acc20 += a.z * bv.x; acc21 += a.z * bv.y;
      acc30 += a.w * bv.x; acc31 += a.w * bv.y;
    }
    __syncthreads();
  }

  const float b0 = bias[c0 + tc];
  const float b1 = bias[c0 + tc + 1];
  float* crow = C + (size_t)(r0 + tr) * N + c0 + tc;
  crow[0] = acc00 + b0; crow[1] = acc01 + b1; crow += N;
  crow[0] = acc10 + b0; crow[1] = acc11 + b1; crow += N;
  crow[0] = acc20 + b0; crow[1] = acc21 + b1; crow += N;
  crow[0] = acc30 + b0; crow[1] = acc31 + b1;
}

// ---------------------------------------------------------------------------
// Fused attention: per block = 64 query rows of one (b,h).
// q_tmp: [b*S+s][96]   (row segment h*12.. is this head's q, 48B aligned)
// k_tmp: [b*S+s][96]
// v_tmp: [b*S+s][256]  (segment h*32.. , 128B aligned)
// Writes normalized p directly to p_out ([bh][S][S]) and attention output to
// x_ws laid out [b][s][h*32+dv] (== transpose(0,2,1,3).reshape).
// Two passes, no max subtraction (scores are small; masked -> e = 0 exactly).
// ---------------------------------------------------------------------------
__global__ __launch_bounds__(256) void attn_kernel(
    const float* __restrict__ q_tmp, const float* __restrict__ k_tmp,
    const float* __restrict__ v_tmp, const int* __restrict__ mask,
    float* __restrict__ p_out, float* __restrict__ x_ws)
{
  const int bh = blockIdx.y;
  const int b  = bh >> 3, h = bh & 7;
  const int r0 = blockIdx.x * 64;
  const int t    = threadIdx.x;
  const int lane = t & 63;
  const int w    = t >> 6;      // wave id 0..3

  __shared__ float q_lds[64][12];      // row-major, 48B rows (float4-aligned)
  __shared__ float e_lds[64][65];      // padded -> conflict-free PV reads
  __shared__ float inv_lds[64];

  // stage q tile (768 consecutive-ish floats; runs of 12)
  for (int j = t; j < 64 * 12; j += 256) {
    const int row = j / 12, d = j % 12;
    q_lds[row][d] = q_tmp[(size_t)(b * S_LEN + r0 + row) * 96 + h * 12 + d];
  }
  __syncthreads();

  const float scale = 0.288675134594813f;  // 1/sqrt(12)
  const float* kbase = k_tmp + (size_t)b * S_LEN * 96 + h * 12;
  const int*   mrow  = mask + b * S_LEN;

  // ---------------- pass 1: row sums of exp ----------------
  float sums[16];
#pragma unroll
  for (int i = 0; i < 16; ++i) sums[i] = 0.f;

  for (int st = 0; st < 32; ++st) {
    const int key = st * 64 + lane;
    const float* kr = kbase + (size_t)key * 96;
    const float4 ka = *reinterpret_cast<const float4*>(kr);
    const float4 kb = *reinterpret_cast<const float4*>(kr + 4);
    const float4 kc = *reinterpret_cast<const float4*>(kr + 8);
    if (mrow[key] != 0) {
#pragma unroll
      for (int i = 0; i < 16; ++i) {
        const int rg = w + 4 * i;
        const float4 qa = *reinterpret_cast<const float4*>(&q_lds[rg][0]);
        const float4 qb = *reinterpret_cast<const float4*>(&q_lds[rg][4]);
        const float4 qc = *reinterpret_cast<const float4*>(&q_lds[rg][8]);
        float s = qa.x * ka.x + qa.y * ka.y + qa.z * ka.z + qa.w * ka.w
                + qb.x * kb.x + qb.y * kb.y + qb.z * kb.z + qb.w * kb.w
                + qc.x * kc.x + qc.y * kc.y + qc.z * kc.z + qc.w * kc.w;
        sums[i] += __expf(s * scale);
      }
    }
  }
#pragma unroll
  for (int i = 0; i < 16; ++i) {
    float s = sums[i];
#pragma unroll
    for (int off = 32; off; off >>= 1) s += __shfl_xor(s, off, 64);
    if (lane == 0) inv_lds[w + 4 * i] = 1.0f / s;
  }
  __syncthreads();

  float inv[16];
#pragma unroll
  for (int i = 0; i < 16; ++i) inv[i] = inv_lds[w + 4 * i];

  // ---------------- pass 2: p write + PV ----------------
  const int rt = t >> 3;          // 0..31 (owns rows rt and rt+32)
  const int dt = (t & 7) * 4;     // dim quad
  float4 accA = {0.f, 0.f, 0.f, 0.f};
  float4 accB = {0.f, 0.f, 0.f, 0.f};
  const float* vbase = v_tmp + (size_t)b * S_LEN * 256 + h * 32 + dt;
  float* pbase = p_out + (size_t)bh * S_LEN * S_LEN + (size_t)r0 * S_LEN;

  for (int st = 0; st < 32; ++st) {
    const int key = st * 64 + lane;
    const float* kr = kbase + (size_t)key * 96;
    const float4 ka = *reinterpret_cast<const float4*>(kr);
    const float4 kb = *reinterpret_cast<const float4*>(kr + 4);
    const float4 kc = *reinterpret_cast<const float4*>(kr + 8);
    const int mv = mrow[key];
#pragma unroll
    for (int i = 0; i < 16; ++i) {
      const int rg = w + 4 * i;
      float e = 0.f;
      if (mv != 0) {
        const float4 qa = *reinterpret_cast<const float4*>(&q_lds[rg][0]);
        const float4 qb = *reinterpret_cast<const float4*>(&q_lds[rg][4]);
        const float4 qc = *reinterpret_cast<const float4*>(&q_lds[rg][8]);
        float s = qa.x * ka.x + qa.y * ka.y + qa.z * ka.z + qa.w * ka.w
                + qb.x * kb.x + qb.y * kb.y + qb.z * kb.z + qb.w * kb.w
                + qc.x * kc.x + qc.y * kc.y + qc.z * kc.z + qc.w * kc.w;
        e = __expf(s * scale) * inv[i];
      }
      e_lds[rg][lane] = e;
      pbase[(size_t)rg * S_LEN + key] = e;
    }
    __syncthreads();
    const float* vrow = vbase + (size_t)st * 64 * 256;
#pragma unroll 8
    for (int kk = 0; kk < 64; ++kk) {
      const float4 v4 = *reinterpret_cast<const float4*>(vrow + (size_t)kk * 256);
      const float e0 = e_lds[rt][kk];
      const float e1 = e_lds[rt + 32][kk];
      accA.x += e0 * v4.x; accA.y += e0 * v4.y; accA.z += e0 * v4.z; accA.w += e0 * v4.w;
      accB.x += e1 * v4.x; accB.y += e1 * v4.y; accB.z += e1 * v4.z; accB.w += e1 * v4.w;
    }
    __syncthreads();
  }

  float* xo = x_ws + (size_t)(b * S_LEN + r0) * 256 + h * 32 + dt;
  *reinterpret_cast<float4*>(xo + (size_t)rt * 256)        = accA;
  *reinterpret_cast<float4*>(xo + (size_t)(rt + 32) * 256) = accB;
}

// ---------------------------------------------------------------------------
extern "C" void kernel_launch(void* const* d_in, const int* in_sizes, int n_in,
                              void* d_out, int out_size, void* d_ws, size_t ws_size,
                              hipStream_t stream) {
  const float* query = (const float*)d_in[0];
  const float* key_  = (const float*)d_in[1];
  const float* value = (const float*)d_in[2];
  const int*   mask  = (const int*)d_in[3];
  const float* Wq = (const float*)d_in[4];
  const float* bq = (const float*)d_in[5];
  const float* Wk = (const float*)d_in[6];
  const float* bk = (const float*)d_in[7];
  const float* Wv = (const float*)d_in[8];
  const float* bv = (const float*)d_in[9];
  const float* Wx = (const float*)d_in[10];
  const float* bx = (const float*)d_in[11];

  const int M = NB * S_LEN;                  // 8192
  float* out_x = (float*)d_out;              // [4,2048,512]
  float* out_p = out_x + (size_t)M * 512;    // [4,8,2048,2048]

  float* ws    = (float*)d_ws;
  float* q_tmp = ws;                         // 8192*96
  float* k_tmp = q_tmp + (size_t)M * 96;     // 8192*96
  float* v_tmp = k_tmp + (size_t)M * 96;     // 8192*256
  float* x_ws  = v_tmp + (size_t)M * 256;    // 8192*256

  // QKV projections
  gemm_bias_kernel<<<dim3(M / 64, 96 / 32), 256, 0, stream>>>(
      query, Wq, bq, q_tmp, M, 96, 512);
  gemm_bias_kernel<<<dim3(M / 64, 96 / 32), 256, 0, stream>>>(
      key_, Wk, bk, k_tmp, M, 96, 512);
  gemm_bias_kernel<<<dim3(M / 64, 256 / 32), 256, 0, stream>>>(
      value, Wv, bv, v_tmp, M, 256, 512);

  // fused attention: grid (row tiles, b*h)
  attn_kernel<<<dim3(S_LEN / 64, NB * NH), 256, 0, stream>>>(
      q_tmp, k_tmp, v_tmp, mask, out_p, x_ws);

  // output projection
  gemm_bias_kernel<<<dim3(M / 64, 512 / 32), 256, 0, stream>>>(
      x_ws, Wx, bx, out_x, M, 512, 256);
}

// Round 2
// 398.514 us; speedup vs baseline: 1.8684x; 1.8684x over previous
//
#include <hip/hip_runtime.h>

#define S_LEN 2048
#define NB 4
#define NH 8

typedef short bfrag8 __attribute__((ext_vector_type(8)));
typedef float f32x16 __attribute__((ext_vector_type(16)));
typedef float f32x4 __attribute__((ext_vector_type(4)));

__device__ __forceinline__ unsigned short f2bf(float x) {
  union { float f; unsigned u; } v; v.f = x;
  unsigned r = v.u + 0x7FFFu + ((v.u >> 16) & 1u);
  return (unsigned short)(r >> 16);
}
__device__ __forceinline__ unsigned pk2(float a, float b) {
  return (unsigned)f2bf(a) | ((unsigned)f2bf(b) << 16);
}

// ---------------------------------------------------------------------------
// Tiled fp32 GEMM with bias: C[M,N] = A[M,K] @ B[K,N] + bias[N]
// 256 threads compute a 128x32 tile, 4x4 per thread.
// transC: write C transposed as [batch][N][2048] (for V^T), batch = row/2048.
// ---------------------------------------------------------------------------
__global__ __launch_bounds__(256) void gemm128(
    const float* __restrict__ A, const float* __restrict__ Bm,
    const float* __restrict__ bias, float* __restrict__ C,
    int M, int N, int K, int transC)
{
  __shared__ float As[16][136];
  __shared__ float Bs[16][36];

  const int t  = threadIdx.x;
  const int r0 = blockIdx.x * 128;
  const int c0 = blockIdx.y * 32;
  const int tr = (t >> 3) * 4;    // 0..124
  const int tc = (t & 7) * 4;     // 0..28

  float acc[4][4];
#pragma unroll
  for (int i = 0; i < 4; ++i)
#pragma unroll
    for (int j = 0; j < 4; ++j) acc[i][j] = 0.f;

  for (int k0 = 0; k0 < K; k0 += 16) {
    for (int j = t; j < 512; j += 256) {
      const int ar = j >> 2, ak = (j & 3) * 4;
      const float4 a4 = *reinterpret_cast<const float4*>(
          A + (size_t)(r0 + ar) * K + k0 + ak);
      As[ak + 0][ar] = a4.x; As[ak + 1][ar] = a4.y;
      As[ak + 2][ar] = a4.z; As[ak + 3][ar] = a4.w;
    }
    for (int j = t; j < 512; j += 256)
      Bs[j >> 5][j & 31] = Bm[(size_t)(k0 + (j >> 5)) * N + c0 + (j & 31)];
    __syncthreads();
#pragma unroll
    for (int kk = 0; kk < 16; ++kk) {
      const float4 av = *reinterpret_cast<const float4*>(&As[kk][tr]);
      const float4 bv = *reinterpret_cast<const float4*>(&Bs[kk][tc]);
      acc[0][0] += av.x * bv.x; acc[0][1] += av.x * bv.y; acc[0][2] += av.x * bv.z; acc[0][3] += av.x * bv.w;
      acc[1][0] += av.y * bv.x; acc[1][1] += av.y * bv.y; acc[1][2] += av.y * bv.z; acc[1][3] += av.y * bv.w;
      acc[2][0] += av.z * bv.x; acc[2][1] += av.z * bv.y; acc[2][2] += av.z * bv.z; acc[2][3] += av.z * bv.w;
      acc[3][0] += av.w * bv.x; acc[3][1] += av.w * bv.y; acc[3][2] += av.w * bv.z; acc[3][3] += av.w * bv.w;
    }
    __syncthreads();
  }

  const float b0 = bias[c0 + tc + 0], b1 = bias[c0 + tc + 1];
  const float b2 = bias[c0 + tc + 2], b3 = bias[c0 + tc + 3];
  if (!transC) {
#pragma unroll
    for (int i = 0; i < 4; ++i) {
      float4 o = make_float4(acc[i][0] + b0, acc[i][1] + b1,
                             acc[i][2] + b2, acc[i][3] + b3);
      *reinterpret_cast<float4*>(C + (size_t)(r0 + tr + i) * N + c0 + tc) = o;
    }
  } else {
    const int bb = r0 >> 11;             // batch (rows of same batch per block)
    const int sr = (r0 & (S_LEN - 1)) + tr;
    const float bj[4] = {b0, b1, b2, b3};
#pragma unroll
    for (int j = 0; j < 4; ++j) {
      float4 o = make_float4(acc[0][j] + bj[j], acc[1][j] + bj[j],
                             acc[2][j] + bj[j], acc[3][j] + bj[j]);
      *reinterpret_cast<float4*>(C + (size_t)(bb * N + c0 + tc + j) * S_LEN + sr) = o;
    }
  }
}

// ---------------------------------------------------------------------------
// MFMA fused attention. Block = 256 thr (4 waves), each wave owns 32 q rows
// (QBLK=128). Swapped QK^T: D' = mfma_32x32x16_bf16(A=K, B=Q^T) so lane
// holds P[row = lane&31] for 16 of 32 keys; partner half via shfl_xor(32).
// Mask folded into pad dim 12: K[12] = mask?0:-1000 (bf16), Q[12] = 64
//   -> masked score = s - 64000 -> expf underflows to exact 0.
// Pass 1: row sums (in-register). Pass 2: recompute, normalize, relayout
// via per-wave p_lds for coalesced NT p-store, PV via 2 more MFMAs/tile.
// ---------------------------------------------------------------------------
__global__ __launch_bounds__(256) void attn_mfma(
    const float* __restrict__ q_tmp, const float* __restrict__ k_tmp,
    const float* __restrict__ vT_tmp, const int* __restrict__ mask,
    float* __restrict__ p_out, float* __restrict__ x_ws)
{
  const int bh = blockIdx.y, b = bh >> 3, h = bh & 7;
  const int q0 = blockIdx.x * 128;
  const int t = threadIdx.x, w = t >> 6, lane = t & 63;
  const int lo = lane & 31, hi = lane >> 5;

  __shared__ __align__(16) unsigned short K_lds[64][16];   // bf16 bits, dim12 = mask term
  __shared__ __align__(16) unsigned short VT_lds[32][72];  // bf16 V^T [dv][key], pad 72
  __shared__ __align__(16) float p_lds[4][32][36];         // per-wave 32x32 P tile

  const float scale = 0.28867513459481287f;  // 1/sqrt(12)

  // ---- Q fragment (B-operand): row q0+32w+lo, k = hi*8 + j (dims 12..15 pad)
  bfrag8 qf;
  {
    const float* qp = q_tmp + (size_t)(b * S_LEN + q0 + 32 * w + lo) * 96 + h * 12;
    if (hi == 0) {
      const float4 a = *reinterpret_cast<const float4*>(qp);
      const float4 c = *reinterpret_cast<const float4*>(qp + 4);
      qf[0] = (short)f2bf(a.x * scale); qf[1] = (short)f2bf(a.y * scale);
      qf[2] = (short)f2bf(a.z * scale); qf[3] = (short)f2bf(a.w * scale);
      qf[4] = (short)f2bf(c.x * scale); qf[5] = (short)f2bf(c.y * scale);
      qf[6] = (short)f2bf(c.z * scale); qf[7] = (short)f2bf(c.w * scale);
    } else {
      const float4 a = *reinterpret_cast<const float4*>(qp + 8);
      qf[0] = (short)f2bf(a.x * scale); qf[1] = (short)f2bf(a.y * scale);
      qf[2] = (short)f2bf(a.z * scale); qf[3] = (short)f2bf(a.w * scale);
      qf[4] = (short)0x4280;  // bf16(64.0) multiplies K's mask slot
      qf[5] = 0; qf[6] = 0; qf[7] = 0;
    }
  }

  const size_t kbase = (size_t)b * S_LEN * 96 + h * 12;
  const int* mrow = mask + b * S_LEN;

  f32x16 zc;
#pragma unroll
  for (int r = 0; r < 16; ++r) zc[r] = 0.f;

  // ---------------- pass 1: row sums ----------------
  float sum = 0.f;
  for (int ch = 0; ch < S_LEN; ch += 64) {
    __syncthreads();
    if (t < 192) {
      const int row = t / 3, seg = t % 3;
      const float4 kv = *reinterpret_cast<const float4*>(
          k_tmp + kbase + (size_t)(ch + row) * 96 + seg * 4);
      unsigned* dst = (unsigned*)&K_lds[row][seg * 4];
      dst[0] = pk2(kv.x, kv.y); dst[1] = pk2(kv.z, kv.w);
    } else {
      const int row = t - 192;
      unsigned* dst = (unsigned*)&K_lds[row][12];
      dst[0] = (mrow[ch + row] != 0) ? 0u : 0xC47Au;  // bf16(-1000) in dim 12
      dst[1] = 0u;
    }
    __syncthreads();
#pragma unroll
    for (int T = 0; T < 2; ++T) {
      const bfrag8 kf = *reinterpret_cast<const bfrag8*>(&K_lds[T * 32 + lo][hi * 8]);
      const f32x16 sc = __builtin_amdgcn_mfma_f32_32x32x16_bf16(kf, qf, zc, 0, 0, 0);
#pragma unroll
      for (int r = 0; r < 16; ++r) sum += __expf(sc[r]);
    }
  }
  sum += __shfl_xor(sum, 32);
  const float inv = 1.0f / sum;

  // ---------------- pass 2: p write + PV ----------------
  f32x16 xacc;
#pragma unroll
  for (int r = 0; r < 16; ++r) xacc[r] = 0.f;

  for (int ch = 0; ch < S_LEN; ch += 64) {
    __syncthreads();
    if (t < 192) {
      const int row = t / 3, seg = t % 3;
      const float4 kv = *reinterpret_cast<const float4*>(
          k_tmp + kbase + (size_t)(ch + row) * 96 + seg * 4);
      unsigned* dst = (unsigned*)&K_lds[row][seg * 4];
      dst[0] = pk2(kv.x, kv.y); dst[1] = pk2(kv.z, kv.w);
    } else {
      const int row = t - 192;
      unsigned* dst = (unsigned*)&K_lds[row][12];
      dst[0] = (mrow[ch + row] != 0) ? 0u : 0xC47Au;
      dst[1] = 0u;
    }
    for (int j = t; j < 512; j += 256) {   // stage V^T chunk (32 dv x 64 keys)
      const int dv = j >> 4, kq = (j & 15) * 4;
      const float4 vv = *reinterpret_cast<const float4*>(
          vT_tmp + (size_t)(b * 256 + h * 32 + dv) * S_LEN + ch + kq);
      unsigned* dst = (unsigned*)&VT_lds[dv][kq];
      dst[0] = pk2(vv.x, vv.y); dst[1] = pk2(vv.z, vv.w);
    }
    __syncthreads();

#pragma unroll
    for (int T = 0; T < 2; ++T) {
      const bfrag8 kf = *reinterpret_cast<const bfrag8*>(&K_lds[T * 32 + lo][hi * 8]);
      const f32x16 sc = __builtin_amdgcn_mfma_f32_32x32x16_bf16(kf, qf, zc, 0, 0, 0);

      // normalize + relayout into per-wave p_lds[row][key] (keys of this lane:
      // (r&3) + 8*(r>>2) + 4*hi  ->  float4 at col qd*8 + hi*4)
#pragma unroll
      for (int qd = 0; qd < 4; ++qd) {
        f32x4 ev;
        ev.x = __expf(sc[qd * 4 + 0]) * inv;
        ev.y = __expf(sc[qd * 4 + 1]) * inv;
        ev.z = __expf(sc[qd * 4 + 2]) * inv;
        ev.w = __expf(sc[qd * 4 + 3]) * inv;
        *reinterpret_cast<f32x4*>(&p_lds[w][lo][qd * 8 + hi * 4]) = ev;
      }

      // coalesced nontemporal p store (8 rows x 32 keys per instruction)
      float* pg = p_out + (size_t)bh * S_LEN * S_LEN
                + (size_t)(q0 + 32 * w) * S_LEN + ch + T * 32;
#pragma unroll
      for (int i = 0; i < 4; ++i) {
        const int row = i * 8 + (lane >> 3);
        const int k4  = (lane & 7) * 4;
        const f32x4 pv = *reinterpret_cast<const f32x4*>(&p_lds[w][row][k4]);
        __builtin_nontemporal_store(pv,
            reinterpret_cast<f32x4*>(pg + (size_t)row * S_LEN + k4));
      }

      // PV: X[32 rows x 32 dv] += P_tile * V_tile  (two K=16 MFMAs)
#pragma unroll
      for (int m = 0; m < 2; ++m) {
        const f32x4 pa = *reinterpret_cast<const f32x4*>(&p_lds[w][lo][m * 16 + hi * 8]);
        const f32x4 pb = *reinterpret_cast<const f32x4*>(&p_lds[w][lo][m * 16 + hi * 8 + 4]);
        bfrag8 af;
        af[0] = (short)f2bf(pa.x); af[1] = (short)f2bf(pa.y);
        af[2] = (short)f2bf(pa.z); af[3] = (short)f2bf(pa.w);
        af[4] = (short)f2bf(pb.x); af[5] = (short)f2bf(pb.y);
        af[6] = (short)f2bf(pb.z); af[7] = (short)f2bf(pb.w);
        const bfrag8 vf = *reinterpret_cast<const bfrag8*>(
            &VT_lds[lo][T * 32 + m * 16 + hi * 8]);
        xacc = __builtin_amdgcn_mfma_f32_32x32x16_bf16(af, vf, xacc, 0, 0, 0);
      }
    }
  }

  // write X: D layout col=dv=lo, row=(r&3)+8*(r>>2)+4*hi
  float* xw = x_ws + (size_t)(b * S_LEN + q0 + 32 * w) * 256 + h * 32 + lo;
#pragma unroll
  for (int r = 0; r < 16; ++r) {
    const int row = (r & 3) + 8 * (r >> 2) + 4 * hi;
    xw[(size_t)row * 256] = xacc[r];
  }
}

// ---------------------------------------------------------------------------
extern "C" void kernel_launch(void* const* d_in, const int* in_sizes, int n_in,
                              void* d_out, int out_size, void* d_ws, size_t ws_size,
                              hipStream_t stream) {
  const float* query = (const float*)d_in[0];
  const float* key_  = (const float*)d_in[1];
  const float* value = (const float*)d_in[2];
  const int*   mask  = (const int*)d_in[3];
  const float* Wq = (const float*)d_in[4];
  const float* bq = (const float*)d_in[5];
  const float* Wk = (const float*)d_in[6];
  const float* bk = (const float*)d_in[7];
  const float* Wv = (const float*)d_in[8];
  const float* bv = (const float*)d_in[9];
  const float* Wx = (const float*)d_in[10];
  const float* bx = (const float*)d_in[11];

  const int M = NB * S_LEN;                  // 8192
  float* out_x = (float*)d_out;              // [4,2048,512]
  float* out_p = out_x + (size_t)M * 512;    // [4,8,2048,2048]

  float* ws     = (float*)d_ws;
  float* q_tmp  = ws;                         // 8192*96
  float* k_tmp  = q_tmp + (size_t)M * 96;     // 8192*96
  float* vT_tmp = k_tmp + (size_t)M * 96;     // 4*256*2048
  float* x_ws   = vT_tmp + (size_t)M * 256;   // 8192*256

  // projections (V written transposed per batch: [4][256][2048])
  gemm128<<<dim3(M / 128, 96 / 32), 256, 0, stream>>>(
      query, Wq, bq, q_tmp, M, 96, 512, 0);
  gemm128<<<dim3(M / 128, 96 / 32), 256, 0, stream>>>(
      key_, Wk, bk, k_tmp, M, 96, 512, 0);
  gemm128<<<dim3(M / 128, 256 / 32), 256, 0, stream>>>(
      value, Wv, bv, vT_tmp, M, 256, 512, 1);

  // fused MFMA attention: grid (q tiles of 128, b*h)
  attn_mfma<<<dim3(S_LEN / 128, NB * NH), 256, 0, stream>>>(
      q_tmp, k_tmp, vT_tmp, mask, out_p, x_ws);

  // output projection
  gemm128<<<dim3(M / 128, 512 / 32), 256, 0, stream>>>(
      x_ws, Wx, bx, out_x, M, 512, 256, 0);
}

// Round 3
// 314.554 us; speedup vs baseline: 2.3671x; 1.2669x over previous
//
#include <hip/hip_runtime.h>

#define S_LEN 2048
#define NB 4
#define NH 8

typedef short bfrag8 __attribute__((ext_vector_type(8)));
typedef float f32x16 __attribute__((ext_vector_type(16)));
typedef float f32x4 __attribute__((ext_vector_type(4)));

__device__ __forceinline__ unsigned short f2bf(float x) {
  union { float f; unsigned u; } v; v.f = x;
  unsigned r = v.u + 0x7FFFu + ((v.u >> 16) & 1u);
  return (unsigned short)(r >> 16);
}

// ---------------------------------------------------------------------------
// Tiled fp32 GEMM, 128x32 tile, 4x4/thread. Epilogue modes:
//  0: fp32 row-major + bias                   (output projection)
//  1: bf16, col remap c -> (c/12)*16 + c%12, * oscale   (q/k, padded heads)
//  2: bf16 transposed [batch][N][2048]        (V^T)
// ---------------------------------------------------------------------------
__global__ __launch_bounds__(256) void gemm128(
    const float* __restrict__ A, const float* __restrict__ Bm,
    const float* __restrict__ bias, float* __restrict__ Cf,
    unsigned short* __restrict__ Cb,
    int M, int N, int K, int mode, float oscale)
{
  __shared__ float As[16][136];
  __shared__ float Bs[16][36];

  const int t  = threadIdx.x;
  const int r0 = blockIdx.x * 128;
  const int c0 = blockIdx.y * 32;
  const int tr = (t >> 3) * 4;
  const int tc = (t & 7) * 4;

  float acc[4][4];
#pragma unroll
  for (int i = 0; i < 4; ++i)
#pragma unroll
    for (int j = 0; j < 4; ++j) acc[i][j] = 0.f;

  for (int k0 = 0; k0 < K; k0 += 16) {
    for (int j = t; j < 512; j += 256) {
      const int ar = j >> 2, ak = (j & 3) * 4;
      const float4 a4 = *reinterpret_cast<const float4*>(
          A + (size_t)(r0 + ar) * K + k0 + ak);
      As[ak + 0][ar] = a4.x; As[ak + 1][ar] = a4.y;
      As[ak + 2][ar] = a4.z; As[ak + 3][ar] = a4.w;
    }
    for (int j = t; j < 512; j += 256)
      Bs[j >> 5][j & 31] = Bm[(size_t)(k0 + (j >> 5)) * N + c0 + (j & 31)];
    __syncthreads();
#pragma unroll
    for (int kk = 0; kk < 16; ++kk) {
      const float4 av = *reinterpret_cast<const float4*>(&As[kk][tr]);
      const float4 bv = *reinterpret_cast<const float4*>(&Bs[kk][tc]);
      acc[0][0] += av.x * bv.x; acc[0][1] += av.x * bv.y; acc[0][2] += av.x * bv.z; acc[0][3] += av.x * bv.w;
      acc[1][0] += av.y * bv.x; acc[1][1] += av.y * bv.y; acc[1][2] += av.y * bv.z; acc[1][3] += av.y * bv.w;
      acc[2][0] += av.z * bv.x; acc[2][1] += av.z * bv.y; acc[2][2] += av.z * bv.z; acc[2][3] += av.z * bv.w;
      acc[3][0] += av.w * bv.x; acc[3][1] += av.w * bv.y; acc[3][2] += av.w * bv.z; acc[3][3] += av.w * bv.w;
    }
    __syncthreads();
  }

  const float bj[4] = {bias[c0 + tc + 0], bias[c0 + tc + 1],
                       bias[c0 + tc + 2], bias[c0 + tc + 3]};
  if (mode == 0) {
#pragma unroll
    for (int i = 0; i < 4; ++i) {
      float4 o = make_float4(acc[i][0] + bj[0], acc[i][1] + bj[1],
                             acc[i][2] + bj[2], acc[i][3] + bj[3]);
      *reinterpret_cast<float4*>(Cf + (size_t)(r0 + tr + i) * N + c0 + tc) = o;
    }
  } else if (mode == 1) {
#pragma unroll
    for (int j = 0; j < 4; ++j) {
      const int c = c0 + tc + j;
      const int off = (c / 12) * 16 + (c % 12);
#pragma unroll
      for (int i = 0; i < 4; ++i)
        Cb[(size_t)(r0 + tr + i) * 128 + off] = f2bf((acc[i][j] + bj[j]) * oscale);
    }
  } else {
    const int bb = r0 >> 11;
    const int sr = (r0 & (S_LEN - 1)) + tr;
#pragma unroll
    for (int j = 0; j < 4; ++j) {
      ushort4 o;
      o.x = f2bf(acc[0][j] + bj[j]); o.y = f2bf(acc[1][j] + bj[j]);
      o.z = f2bf(acc[2][j] + bj[j]); o.w = f2bf(acc[3][j] + bj[j]);
      *reinterpret_cast<ushort4*>(Cb + (size_t)(bb * N + c0 + tc + j) * S_LEN + sr) = o;
    }
  }
}

// Fill pad dims 12..15 of q_bf/k_bf: q pad = {1.0, 0,0,0};
// k pad = {mask ? 0 : bf16(-1e9), 0,0,0} -> masked score ~ -1e9, exp -> 0.
__global__ __launch_bounds__(256) void fill_pads(
    const int* __restrict__ mask,
    unsigned short* __restrict__ q_bf, unsigned short* __restrict__ k_bf)
{
  const int i = blockIdx.x * 256 + threadIdx.x;   // over NB*S*NH = 65536
  const int h = i & 7;
  const int s = (i >> 3) & (S_LEN - 1);
  const int b = i >> 14;
  const size_t base = (size_t)(b * S_LEN + s) * 128 + h * 16 + 12;
  ushort4 qp; qp.x = 0x3F80; qp.y = 0; qp.z = 0; qp.w = 0;
  ushort4 kp; kp.x = (mask[b * S_LEN + s] != 0) ? (unsigned short)0
                                                : (unsigned short)0xCE6E;
  kp.y = 0; kp.z = 0; kp.w = 0;
  *reinterpret_cast<ushort4*>(q_bf + base) = qp;
  *reinterpret_cast<ushort4*>(k_bf + base) = kp;
}

// ---------------------------------------------------------------------------
// MFMA attention, occupancy-oriented: block = 32 q rows of one (b,h), 4 waves
// split the key dim (each wave: 8 chunks of 64 keys). Fragments loaded
// directly from global bf16 (no staging). Barriers: 1 (sum reduce) + 2 (xacc
// reduce). Swapped QK^T: mfma(A=K, B=Q^T) -> lane(lo,hi) holds 16 keys for
// q-row lo. Mask folded into pad dim 12 (see fill_pads).
// ---------------------------------------------------------------------------
__global__ __launch_bounds__(256) void attn_mfma(
    const unsigned short* __restrict__ q_bf,
    const unsigned short* __restrict__ k_bf,
    const unsigned short* __restrict__ vT_bf,
    float* __restrict__ p_out, float* __restrict__ x_ws)
{
  const int bh = blockIdx.y, b = bh >> 3, h = bh & 7;
  const int q0 = blockIdx.x * 32;
  const int t = threadIdx.x, w = t >> 6, lane = t & 63;
  const int lo = lane & 31, hi = lane >> 5;

  __shared__ float red_lds[4][32];
  __shared__ __align__(16) char smbuf[4 * 64 * 20 * 4];  // p[4][32][36] | xr[4][64][20]
  float (*p_lds)[32][36] = reinterpret_cast<float (*)[32][36]>(smbuf);
  float (*xr)[64][20]    = reinterpret_cast<float (*)[64][20]>(smbuf);

  const bfrag8 qf = *reinterpret_cast<const bfrag8*>(
      q_bf + (size_t)(b * S_LEN + q0 + lo) * 128 + h * 16 + hi * 8);
  const unsigned short* kbase = k_bf + (size_t)b * S_LEN * 128 + h * 16 + hi * 8;

  f32x16 zc;
#pragma unroll
  for (int r = 0; r < 16; ++r) zc[r] = 0.f;

  // ---------------- pass 1: row sums (no barriers, no LDS) ----------------
  float sum = 0.f;
  for (int ch = w * 64; ch < S_LEN; ch += 256) {
#pragma unroll
    for (int T = 0; T < 2; ++T) {
      const bfrag8 kf = *reinterpret_cast<const bfrag8*>(
          kbase + (size_t)(ch + T * 32 + lo) * 128);
      const f32x16 sc = __builtin_amdgcn_mfma_f32_32x32x16_bf16(kf, qf, zc, 0, 0, 0);
#pragma unroll
      for (int r = 0; r < 16; ++r) sum += __expf(sc[r]);
    }
  }
  sum += __shfl_xor(sum, 32);
  if (hi == 0) red_lds[w][lo] = sum;
  __syncthreads();
  const float inv = 1.0f /
      (red_lds[0][lo] + red_lds[1][lo] + red_lds[2][lo] + red_lds[3][lo]);

  // ---------------- pass 2: p write + PV (wave-private LDS only) ----------
  f32x16 xacc;
#pragma unroll
  for (int r = 0; r < 16; ++r) xacc[r] = 0.f;

  const unsigned short* vbase = vT_bf + (size_t)(b * 256 + h * 32 + lo) * S_LEN;
  float* pg0 = p_out + (size_t)bh * S_LEN * S_LEN + (size_t)q0 * S_LEN;

  for (int ch = w * 64; ch < S_LEN; ch += 256) {
#pragma unroll
    for (int T = 0; T < 2; ++T) {
      const bfrag8 kf = *reinterpret_cast<const bfrag8*>(
          kbase + (size_t)(ch + T * 32 + lo) * 128);
      const f32x16 sc = __builtin_amdgcn_mfma_f32_32x32x16_bf16(kf, qf, zc, 0, 0, 0);

      // normalize + relayout: lane's keys are (r&3)+8*(r>>2)+4*hi
#pragma unroll
      for (int qd = 0; qd < 4; ++qd) {
        f32x4 ev;
        ev.x = __expf(sc[qd * 4 + 0]) * inv;
        ev.y = __expf(sc[qd * 4 + 1]) * inv;
        ev.z = __expf(sc[qd * 4 + 2]) * inv;
        ev.w = __expf(sc[qd * 4 + 3]) * inv;
        *reinterpret_cast<f32x4*>(&p_lds[w][lo][qd * 8 + hi * 4]) = ev;
      }

      // coalesced NT p store (within-wave LDS; no barrier needed)
      float* pg = pg0 + ch + T * 32;
#pragma unroll
      for (int i = 0; i < 4; ++i) {
        const int row = i * 8 + (lane >> 3);
        const int k4  = (lane & 7) * 4;
        const f32x4 pv = *reinterpret_cast<const f32x4*>(&p_lds[w][row][k4]);
        __builtin_nontemporal_store(pv,
            reinterpret_cast<f32x4*>(pg + (size_t)row * S_LEN + k4));
      }

      // PV: X += P_tile(32x32) * V_tile(32x32), two K=16 MFMAs
#pragma unroll
      for (int m = 0; m < 2; ++m) {
        const f32x4 pa = *reinterpret_cast<const f32x4*>(&p_lds[w][lo][m * 16 + hi * 8]);
        const f32x4 pb = *reinterpret_cast<const f32x4*>(&p_lds[w][lo][m * 16 + hi * 8 + 4]);
        bfrag8 af;
        af[0] = (short)f2bf(pa.x); af[1] = (short)f2bf(pa.y);
        af[2] = (short)f2bf(pa.z); af[3] = (short)f2bf(pa.w);
        af[4] = (short)f2bf(pb.x); af[5] = (short)f2bf(pb.y);
        af[6] = (short)f2bf(pb.z); af[7] = (short)f2bf(pb.w);
        const bfrag8 vf = *reinterpret_cast<const bfrag8*>(
            vbase + ch + T * 32 + m * 16 + hi * 8);
        xacc = __builtin_amdgcn_mfma_f32_32x32x16_bf16(af, vf, xacc, 0, 0, 0);
      }
    }
  }

  // ---------------- cross-wave X reduce ----------------
  __syncthreads();            // all waves done with p_lds (aliased by xr)
#pragma unroll
  for (int r = 0; r < 16; r += 4) {
    f32x4 v4; v4.x = xacc[r]; v4.y = xacc[r + 1]; v4.z = xacc[r + 2]; v4.w = xacc[r + 3];
    *reinterpret_cast<f32x4*>(&xr[w][lane][r]) = v4;
  }
  __syncthreads();
  float xs[4];
#pragma unroll
  for (int j = 0; j < 4; ++j) {
    const int rr = w * 4 + j;
    xs[j] = xr[0][lane][rr] + xr[1][lane][rr] + xr[2][lane][rr] + xr[3][lane][rr];
  }
  float* xw = x_ws + (size_t)(b * S_LEN + q0) * 256 + h * 32 + lo;
#pragma unroll
  for (int j = 0; j < 4; ++j) {
    const int row = j + 8 * w + 4 * hi;   // r = 4w+j -> (r&3)+8*(r>>2)+4*hi
    xw[(size_t)row * 256] = xs[j];
  }
}

// ---------------------------------------------------------------------------
extern "C" void kernel_launch(void* const* d_in, const int* in_sizes, int n_in,
                              void* d_out, int out_size, void* d_ws, size_t ws_size,
                              hipStream_t stream) {
  const float* query = (const float*)d_in[0];
  const float* key_  = (const float*)d_in[1];
  const float* value = (const float*)d_in[2];
  const int*   mask  = (const int*)d_in[3];
  const float* Wq = (const float*)d_in[4];
  const float* bq = (const float*)d_in[5];
  const float* Wk = (const float*)d_in[6];
  const float* bk = (const float*)d_in[7];
  const float* Wv = (const float*)d_in[8];
  const float* bv = (const float*)d_in[9];
  const float* Wx = (const float*)d_in[10];
  const float* bx = (const float*)d_in[11];

  const int M = NB * S_LEN;                  // 8192
  float* out_x = (float*)d_out;              // [4,2048,512]
  float* out_p = out_x + (size_t)M * 512;    // [4,8,2048,2048]

  unsigned short* q_bf  = (unsigned short*)d_ws;            // 8192*128 bf16
  unsigned short* k_bf  = q_bf + (size_t)M * 128;           // 8192*128 bf16
  unsigned short* vT_bf = k_bf + (size_t)M * 128;           // 4*256*2048 bf16
  float* x_ws = (float*)(vT_bf + (size_t)NB * 256 * S_LEN); // 8192*256 f32

  const float qscale = 0.28867513459481287f;  // 1/sqrt(12)

  gemm128<<<dim3(M / 128, 96 / 32), 256, 0, stream>>>(
      query, Wq, bq, nullptr, q_bf, M, 96, 512, 1, qscale);
  gemm128<<<dim3(M / 128, 96 / 32), 256, 0, stream>>>(
      key_, Wk, bk, nullptr, k_bf, M, 96, 512, 1, 1.0f);
  fill_pads<<<NB * S_LEN * NH / 256, 256, 0, stream>>>(mask, q_bf, k_bf);
  gemm128<<<dim3(M / 128, 256 / 32), 256, 0, stream>>>(
      value, Wv, bv, nullptr, vT_bf, M, 256, 512, 2, 1.0f);

  attn_mfma<<<dim3(S_LEN / 32, NB * NH), 256, 0, stream>>>(
      q_bf, k_bf, vT_bf, out_p, x_ws);

  gemm128<<<dim3(M / 128, 512 / 32), 256, 0, stream>>>(
      x_ws, Wx, bx, out_x, nullptr, M, 512, 256, 0, 1.0f);
}

// Round 4
// 190.599 us; speedup vs baseline: 3.9065x; 1.6503x over previous
//
#include <hip/hip_runtime.h>

#define S_LEN 2048
#define NB 4
#define NH 8

typedef short bfrag8 __attribute__((ext_vector_type(8)));
typedef float f32x16 __attribute__((ext_vector_type(16)));
typedef float f32x4 __attribute__((ext_vector_type(4)));

__device__ __forceinline__ unsigned short f2bf(float x) {
  union { float f; unsigned u; } v; v.f = x;
  unsigned r = v.u + 0x7FFFu + ((v.u >> 16) & 1u);
  return (unsigned short)(r >> 16);
}

// ---------------------------------------------------------------------------
// Cast query/key/value fp32 -> bf16, contiguous [3][8192][512], float4 at a time.
// ---------------------------------------------------------------------------
__global__ __launch_bounds__(256) void cast_qkv(
    const float* __restrict__ q, const float* __restrict__ k,
    const float* __restrict__ v, unsigned short* __restrict__ dst)
{
  const size_t i4 = (size_t)blockIdx.x * 256 + threadIdx.x;  // 0 .. 3*1048576-1
  const size_t per = (size_t)8192 * 512 / 4;
  const float* src = (i4 < per) ? q : (i4 < 2 * per ? k : v);
  const size_t off = (i4 % per) * 4;
  const float4 vv = *reinterpret_cast<const float4*>(src + off);
  ushort4 o;
  o.x = f2bf(vv.x); o.y = f2bf(vv.y); o.z = f2bf(vv.z); o.w = f2bf(vv.w);
  *reinterpret_cast<ushort4*>(dst + i4 * 4) = o;
}

// ---------------------------------------------------------------------------
// Transpose weights to bf16 W^T (tiny): WqT/WkT[96][512], WvT[256][512],
// WxT[512][256].
// ---------------------------------------------------------------------------
__global__ __launch_bounds__(256) void transpose_w(
    const float* __restrict__ Wq, const float* __restrict__ Wk,
    const float* __restrict__ Wv, const float* __restrict__ Wx,
    unsigned short* __restrict__ wqT, unsigned short* __restrict__ wkT,
    unsigned short* __restrict__ wvT, unsigned short* __restrict__ wxT)
{
  int i = blockIdx.x * 256 + threadIdx.x;
  if (i < 49152) {
    const int n = i / 512, kk = i % 512;
    wqT[i] = f2bf(Wq[(size_t)kk * 96 + n]);
  } else if (i < 98304) {
    i -= 49152; const int n = i / 512, kk = i % 512;
    wkT[i] = f2bf(Wk[(size_t)kk * 96 + n]);
  } else if (i < 229376) {
    i -= 98304; const int n = i / 512, kk = i % 512;
    wvT[i] = f2bf(Wv[(size_t)kk * 256 + n]);
  } else if (i < 360448) {
    i -= 229376; const int n = i / 256, kk = i % 256;
    wxT[i] = f2bf(Wx[(size_t)kk * 512 + n]);
  }
}

// ---------------------------------------------------------------------------
// LDS-free, barrier-free MFMA GEMM: C[M,N] = A[M,K](bf16) @ BT^T + bias.
// Block 256 thr / 4 waves; wave w computes rows r0=bx*128+32w .. +31, cols
// c0=by*32 .. +31 via 32x32x16 MFMAs, fragments loaded directly from global.
// MODE 0: fp32 row-major out (lane=col -> 128B-coalesced stores)
// MODE 1: bf16 padded-head layout [row][128], col remap c->(c/12)*16+c%12,
//         scaled by oscale (lane=col -> 64B-coalesced)
// MODE 2: bf16 V^T out [b][N][2048] (lane=s-row -> 64B-coalesced)
// ---------------------------------------------------------------------------
template <int MODE>
__global__ __launch_bounds__(256) void gemm_mfma(
    const unsigned short* __restrict__ A, const unsigned short* __restrict__ BT,
    const float* __restrict__ bias, float* __restrict__ Cf,
    unsigned short* __restrict__ Cb, int M, int N, int K, float oscale)
{
  const int t = threadIdx.x, w = t >> 6, lane = t & 63;
  const int lo = lane & 31, hi = lane >> 5;
  const int r0 = blockIdx.x * 128 + 32 * w;
  const int c0 = blockIdx.y * 32;

  const unsigned short* ap = A + (size_t)(r0 + lo) * K + hi * 8;
  const unsigned short* bp = BT + (size_t)(c0 + lo) * K + hi * 8;

  f32x16 acc;
#pragma unroll
  for (int r = 0; r < 16; ++r) acc[r] = 0.f;

  for (int k0 = 0; k0 < K; k0 += 16) {
    const bfrag8 af = *reinterpret_cast<const bfrag8*>(ap + k0);
    const bfrag8 bf = *reinterpret_cast<const bfrag8*>(bp + k0);
    if constexpr (MODE == 2)
      acc = __builtin_amdgcn_mfma_f32_32x32x16_bf16(bf, af, acc, 0, 0, 0);
    else
      acc = __builtin_amdgcn_mfma_f32_32x32x16_bf16(af, bf, acc, 0, 0, 0);
  }

  if constexpr (MODE == 0) {
    const int c = c0 + lo;
    const float bc = bias[c];
#pragma unroll
    for (int r = 0; r < 16; ++r) {
      const int grow = r0 + (r & 3) + 8 * (r >> 2) + 4 * hi;
      Cf[(size_t)grow * N + c] = acc[r] + bc;
    }
  } else if constexpr (MODE == 1) {
    const int c = c0 + lo;
    const int off = (c / 12) * 16 + (c % 12);
    const float bc = bias[c];
#pragma unroll
    for (int r = 0; r < 16; ++r) {
      const int grow = r0 + (r & 3) + 8 * (r >> 2) + 4 * hi;
      Cb[(size_t)grow * 128 + off] = f2bf((acc[r] + bc) * oscale);
    }
  } else {
    const int s = r0 + lo;
    const int bb = s >> 11, sl = s & (S_LEN - 1);
#pragma unroll
    for (int r = 0; r < 16; ++r) {
      const int c = c0 + (r & 3) + 8 * (r >> 2) + 4 * hi;
      Cb[((size_t)(bb * N + c)) * S_LEN + sl] = f2bf(acc[r] + bias[c]);
    }
  }
}

// Fill pad dims 12..15 of q_bf/k_bf: q pad = {1.0,0,0,0};
// k pad = {mask?0:bf16(-1e9),0,0,0} -> masked score ~ -1e9, exp -> 0.
__global__ __launch_bounds__(256) void fill_pads(
    const int* __restrict__ mask,
    unsigned short* __restrict__ q_bf, unsigned short* __restrict__ k_bf)
{
  const int i = blockIdx.x * 256 + threadIdx.x;   // NB*S*NH = 65536
  const int h = i & 7;
  const int s = (i >> 3) & (S_LEN - 1);
  const int b = i >> 14;
  const size_t base = (size_t)(b * S_LEN + s) * 128 + h * 16 + 12;
  ushort4 qp; qp.x = 0x3F80; qp.y = 0; qp.z = 0; qp.w = 0;
  ushort4 kp; kp.x = (mask[b * S_LEN + s] != 0) ? (unsigned short)0
                                                : (unsigned short)0xCE6E;
  kp.y = 0; kp.z = 0; kp.w = 0;
  *reinterpret_cast<ushort4*>(q_bf + base) = qp;
  *reinterpret_cast<ushort4*>(k_bf + base) = kp;
}

// ---------------------------------------------------------------------------
// MFMA attention (round-3 structure) + XCD-aware swizzle (4 consecutive bh
// per XCD -> ~1MB L2 working set) + bf16 x output.
// ---------------------------------------------------------------------------
__global__ __launch_bounds__(256) void attn_mfma(
    const unsigned short* __restrict__ q_bf,
    const unsigned short* __restrict__ k_bf,
    const unsigned short* __restrict__ vT_bf,
    float* __restrict__ p_out, unsigned short* __restrict__ x_bf)
{
  const int id = blockIdx.x + blockIdx.y * 64;       // 0..2047
  const int xcd = id & 7, jj = id >> 3;
  const int bh = 4 * xcd + (jj >> 6);                // 4 bh per XCD
  const int q0 = (jj & 63) * 32;
  const int b = bh >> 3, h = bh & 7;
  const int t = threadIdx.x, w = t >> 6, lane = t & 63;
  const int lo = lane & 31, hi = lane >> 5;

  __shared__ float red_lds[4][32];
  __shared__ __align__(16) char smbuf[4 * 64 * 20 * 4];  // p[4][32][36] | xr[4][64][20]
  float (*p_lds)[32][36] = reinterpret_cast<float (*)[32][36]>(smbuf);
  float (*xr)[64][20]    = reinterpret_cast<float (*)[64][20]>(smbuf);

  const bfrag8 qf = *reinterpret_cast<const bfrag8*>(
      q_bf + (size_t)(b * S_LEN + q0 + lo) * 128 + h * 16 + hi * 8);
  const unsigned short* kbase = k_bf + (size_t)b * S_LEN * 128 + h * 16 + hi * 8;

  f32x16 zc;
#pragma unroll
  for (int r = 0; r < 16; ++r) zc[r] = 0.f;

  // ---------------- pass 1: row sums ----------------
  float sum = 0.f;
  for (int ch = w * 64; ch < S_LEN; ch += 256) {
#pragma unroll
    for (int T = 0; T < 2; ++T) {
      const bfrag8 kf = *reinterpret_cast<const bfrag8*>(
          kbase + (size_t)(ch + T * 32 + lo) * 128);
      const f32x16 sc = __builtin_amdgcn_mfma_f32_32x32x16_bf16(kf, qf, zc, 0, 0, 0);
#pragma unroll
      for (int r = 0; r < 16; ++r) sum += __expf(sc[r]);
    }
  }
  sum += __shfl_xor(sum, 32);
  if (hi == 0) red_lds[w][lo] = sum;
  __syncthreads();
  const float inv = 1.0f /
      (red_lds[0][lo] + red_lds[1][lo] + red_lds[2][lo] + red_lds[3][lo]);

  // ---------------- pass 2: p write + PV ----------------
  f32x16 xacc;
#pragma unroll
  for (int r = 0; r < 16; ++r) xacc[r] = 0.f;

  const unsigned short* vbase = vT_bf + (size_t)(b * 256 + h * 32 + lo) * S_LEN;
  float* pg0 = p_out + (size_t)bh * S_LEN * S_LEN + (size_t)q0 * S_LEN;

  for (int ch = w * 64; ch < S_LEN; ch += 256) {
#pragma unroll
    for (int T = 0; T < 2; ++T) {
      const bfrag8 kf = *reinterpret_cast<const bfrag8*>(
          kbase + (size_t)(ch + T * 32 + lo) * 128);
      const f32x16 sc = __builtin_amdgcn_mfma_f32_32x32x16_bf16(kf, qf, zc, 0, 0, 0);

#pragma unroll
      for (int qd = 0; qd < 4; ++qd) {
        f32x4 ev;
        ev.x = __expf(sc[qd * 4 + 0]) * inv;
        ev.y = __expf(sc[qd * 4 + 1]) * inv;
        ev.z = __expf(sc[qd * 4 + 2]) * inv;
        ev.w = __expf(sc[qd * 4 + 3]) * inv;
        *reinterpret_cast<f32x4*>(&p_lds[w][lo][qd * 8 + hi * 4]) = ev;
      }

      float* pg = pg0 + ch + T * 32;
#pragma unroll
      for (int i = 0; i < 4; ++i) {
        const int row = i * 8 + (lane >> 3);
        const int k4  = (lane & 7) * 4;
        const f32x4 pv = *reinterpret_cast<const f32x4*>(&p_lds[w][row][k4]);
        __builtin_nontemporal_store(pv,
            reinterpret_cast<f32x4*>(pg + (size_t)row * S_LEN + k4));
      }

#pragma unroll
      for (int m = 0; m < 2; ++m) {
        const f32x4 pa = *reinterpret_cast<const f32x4*>(&p_lds[w][lo][m * 16 + hi * 8]);
        const f32x4 pb = *reinterpret_cast<const f32x4*>(&p_lds[w][lo][m * 16 + hi * 8 + 4]);
        bfrag8 af;
        af[0] = (short)f2bf(pa.x); af[1] = (short)f2bf(pa.y);
        af[2] = (short)f2bf(pa.z); af[3] = (short)f2bf(pa.w);
        af[4] = (short)f2bf(pb.x); af[5] = (short)f2bf(pb.y);
        af[6] = (short)f2bf(pb.z); af[7] = (short)f2bf(pb.w);
        const bfrag8 vf = *reinterpret_cast<const bfrag8*>(
            vbase + ch + T * 32 + m * 16 + hi * 8);
        xacc = __builtin_amdgcn_mfma_f32_32x32x16_bf16(af, vf, xacc, 0, 0, 0);
      }
    }
  }

  // ---------------- cross-wave X reduce + bf16 write ----------------
  __syncthreads();
#pragma unroll
  for (int r = 0; r < 16; r += 4) {
    f32x4 v4; v4.x = xacc[r]; v4.y = xacc[r + 1]; v4.z = xacc[r + 2]; v4.w = xacc[r + 3];
    *reinterpret_cast<f32x4*>(&xr[w][lane][r]) = v4;
  }
  __syncthreads();
  unsigned short* xw = x_bf + (size_t)(b * S_LEN + q0) * 256 + h * 32 + lo;
#pragma unroll
  for (int j = 0; j < 4; ++j) {
    const int rr = w * 4 + j;
    const float xs = xr[0][lane][rr] + xr[1][lane][rr]
                   + xr[2][lane][rr] + xr[3][lane][rr];
    const int row = j + 8 * w + 4 * hi;
    xw[(size_t)row * 256] = f2bf(xs);
  }
}

// ---------------------------------------------------------------------------
extern "C" void kernel_launch(void* const* d_in, const int* in_sizes, int n_in,
                              void* d_out, int out_size, void* d_ws, size_t ws_size,
                              hipStream_t stream) {
  const float* query = (const float*)d_in[0];
  const float* key_  = (const float*)d_in[1];
  const float* value = (const float*)d_in[2];
  const int*   mask  = (const int*)d_in[3];
  const float* Wq = (const float*)d_in[4];
  const float* bq = (const float*)d_in[5];
  const float* Wk = (const float*)d_in[6];
  const float* bk = (const float*)d_in[7];
  const float* Wv = (const float*)d_in[8];
  const float* bv = (const float*)d_in[9];
  const float* Wx = (const float*)d_in[10];
  const float* bx = (const float*)d_in[11];

  const int M = NB * S_LEN;                  // 8192
  float* out_x = (float*)d_out;              // [4,2048,512]
  float* out_p = out_x + (size_t)M * 512;    // [4,8,2048,2048]

  unsigned short* qkv_bf = (unsigned short*)d_ws;           // 3*8192*512
  unsigned short* wqT = qkv_bf + (size_t)3 * M * 512;       // 96*512
  unsigned short* wkT = wqT + 49152;                        // 96*512
  unsigned short* wvT = wkT + 49152;                        // 256*512
  unsigned short* wxT = wvT + 131072;                       // 512*256
  unsigned short* q_bf = wxT + 131072;                      // 8192*128
  unsigned short* k_bf = q_bf + (size_t)M * 128;            // 8192*128
  unsigned short* vT_bf = k_bf + (size_t)M * 128;           // 4*256*2048
  unsigned short* x_bf = vT_bf + (size_t)NB * 256 * S_LEN;  // 8192*256

  const float qscale = 0.28867513459481287f;  // 1/sqrt(12)

  cast_qkv<<<3 * M * 512 / 4 / 256, 256, 0, stream>>>(query, key_, value, qkv_bf);
  transpose_w<<<1408, 256, 0, stream>>>(Wq, Wk, Wv, Wx, wqT, wkT, wvT, wxT);

  const unsigned short* qb = qkv_bf;
  const unsigned short* kb = qkv_bf + (size_t)M * 512;
  const unsigned short* vb = qkv_bf + (size_t)2 * M * 512;

  gemm_mfma<1><<<dim3(M / 128, 3), 256, 0, stream>>>(
      qb, wqT, bq, nullptr, q_bf, M, 96, 512, qscale);
  gemm_mfma<1><<<dim3(M / 128, 3), 256, 0, stream>>>(
      kb, wkT, bk, nullptr, k_bf, M, 96, 512, 1.0f);
  gemm_mfma<2><<<dim3(M / 128, 8), 256, 0, stream>>>(
      vb, wvT, bv, nullptr, vT_bf, M, 256, 512, 1.0f);
  fill_pads<<<NB * S_LEN * NH / 256, 256, 0, stream>>>(mask, q_bf, k_bf);

  attn_mfma<<<dim3(S_LEN / 32, NB * NH), 256, 0, stream>>>(
      q_bf, k_bf, vT_bf, out_p, x_bf);

  gemm_mfma<0><<<dim3(M / 128, 16), 256, 0, stream>>>(
      x_bf, wxT, bx, out_x, nullptr, M, 512, 256, 1.0f);
}

// Round 5
// 170.280 us; speedup vs baseline: 4.3726x; 1.1193x over previous
//
#include <hip/hip_runtime.h>

#define S_LEN 2048
#define NB 4
#define NH 8

typedef short bfrag8 __attribute__((ext_vector_type(8)));
typedef float f32x16 __attribute__((ext_vector_type(16)));
typedef float f32x4 __attribute__((ext_vector_type(4)));

__device__ __forceinline__ unsigned short f2bf(float x) {
  union { float f; unsigned u; } v; v.f = x;
  unsigned r = v.u + 0x7FFFu + ((v.u >> 16) & 1u);
  return (unsigned short)(r >> 16);
}

// ---------------------------------------------------------------------------
// Transpose weights to bf16 W^T (tiny): WqT/WkT[96][512], WvT[256][512],
// WxT[512][256].
// ---------------------------------------------------------------------------
__global__ __launch_bounds__(256) void transpose_w(
    const float* __restrict__ Wq, const float* __restrict__ Wk,
    const float* __restrict__ Wv, const float* __restrict__ Wx,
    unsigned short* __restrict__ wqT, unsigned short* __restrict__ wkT,
    unsigned short* __restrict__ wvT, unsigned short* __restrict__ wxT)
{
  int i = blockIdx.x * 256 + threadIdx.x;
  if (i < 49152) {
    const int n = i / 512, kk = i % 512;
    wqT[i] = f2bf(Wq[(size_t)kk * 96 + n]);
  } else if (i < 98304) {
    i -= 49152; const int n = i / 512, kk = i % 512;
    wkT[i] = f2bf(Wk[(size_t)kk * 96 + n]);
  } else if (i < 229376) {
    i -= 98304; const int n = i / 512, kk = i % 512;
    wvT[i] = f2bf(Wv[(size_t)kk * 256 + n]);
  } else if (i < 360448) {
    i -= 229376; const int n = i / 256, kk = i % 256;
    wxT[i] = f2bf(Wx[(size_t)kk * 512 + n]);
  }
}

// ---------------------------------------------------------------------------
// Fused QKV projection, LDS-free MFMA, fp32 A loaded directly (cast fused),
// pad/mask fill fused into epilogue. Grid: 512 blocks, XCD-swizzled:
//   id -> xcd = id&7, j = id>>3; bxl = j&7 (fast), ys = j>>3 (slow)
//   bx = xcd*8 + bxl  (each XCD owns 8 row-panels; A panel 2MB fits L2,
//   re-used across ys tiles of the same tensor)
// ys 0..2: q col-tile ys     -> q_bf (padded-head layout, * qscale)
// ys 3..5: k col-tile ys-3   -> k_bf (padded-head layout, mask in pad slot)
// ys 6..7: v, 4 col-tiles    -> vT_bf [b][256][2048] (swapped-operand MFMA)
// ---------------------------------------------------------------------------
__global__ __launch_bounds__(256) void proj_qkv(
    const float* __restrict__ query, const float* __restrict__ key_,
    const float* __restrict__ value, const int* __restrict__ mask,
    const unsigned short* __restrict__ wqT, const unsigned short* __restrict__ wkT,
    const unsigned short* __restrict__ wvT,
    const float* __restrict__ bq, const float* __restrict__ bk,
    const float* __restrict__ bv,
    unsigned short* __restrict__ q_bf, unsigned short* __restrict__ k_bf,
    unsigned short* __restrict__ vT_bf, float qscale)
{
  const int id = blockIdx.x;
  const int xcd = id & 7, j = id >> 3;
  const int bxl = j & 7, ys = j >> 3;
  const int bx = xcd * 8 + bxl;
  const int t = threadIdx.x, w = t >> 6, lane = t & 63;
  const int lo = lane & 31, hi = lane >> 5;
  const int r0 = bx * 128 + 32 * w;

  if (ys < 6) {
    const bool isq = (ys < 3);
    const float* A = isq ? query : key_;
    const unsigned short* BT = isq ? wqT : wkT;
    const float* bias = isq ? bq : bk;
    unsigned short* Cb = isq ? q_bf : k_bf;
    const float osc = isq ? qscale : 1.0f;
    const int c0 = (isq ? ys : ys - 3) * 32;

    const float* ap = A + (size_t)(r0 + lo) * 512 + hi * 8;
    const unsigned short* bp = BT + (size_t)(c0 + lo) * 512 + hi * 8;

    f32x16 acc;
#pragma unroll
    for (int r = 0; r < 16; ++r) acc[r] = 0.f;

    for (int k0 = 0; k0 < 512; k0 += 16) {
      const float4 a0 = *reinterpret_cast<const float4*>(ap + k0);
      const float4 a1 = *reinterpret_cast<const float4*>(ap + k0 + 4);
      bfrag8 af;
      af[0] = (short)f2bf(a0.x); af[1] = (short)f2bf(a0.y);
      af[2] = (short)f2bf(a0.z); af[3] = (short)f2bf(a0.w);
      af[4] = (short)f2bf(a1.x); af[5] = (short)f2bf(a1.y);
      af[6] = (short)f2bf(a1.z); af[7] = (short)f2bf(a1.w);
      const bfrag8 bf = *reinterpret_cast<const bfrag8*>(bp + k0);
      acc = __builtin_amdgcn_mfma_f32_32x32x16_bf16(af, bf, acc, 0, 0, 0);
    }

    const int c = c0 + lo;
    const int off = (c / 12) * 16 + (c % 12);
    const float bc = bias[c];
#pragma unroll
    for (int r = 0; r < 16; ++r) {
      const int grow = r0 + (r & 3) + 8 * (r >> 2) + 4 * hi;
      Cb[(size_t)grow * 128 + off] = f2bf((acc[r] + bc) * osc);
    }
    // fused pad fill: one lane per head per tile (c multiple of 12)
    if ((c % 12) == 0) {
      const int hh = c / 12;
#pragma unroll
      for (int r = 0; r < 16; ++r) {
        const int grow = r0 + (r & 3) + 8 * (r >> 2) + 4 * hi;
        ushort4 pv;
        pv.x = isq ? (unsigned short)0x3F80
                   : ((mask[grow] != 0) ? (unsigned short)0
                                        : (unsigned short)0xCE6E);
        pv.y = 0; pv.z = 0; pv.w = 0;
        *reinterpret_cast<ushort4*>(Cb + (size_t)grow * 128 + hh * 16 + 12) = pv;
      }
    }
  } else {
    const int ct0 = (ys - 6) * 128;
    const float* ap = value + (size_t)(r0 + lo) * 512 + hi * 8;
    const unsigned short* bp = wvT + (size_t)(ct0 + lo) * 512 + hi * 8;

    f32x16 acc[4];
#pragma unroll
    for (int tt = 0; tt < 4; ++tt)
#pragma unroll
      for (int r = 0; r < 16; ++r) acc[tt][r] = 0.f;

    for (int k0 = 0; k0 < 512; k0 += 16) {
      const float4 a0 = *reinterpret_cast<const float4*>(ap + k0);
      const float4 a1 = *reinterpret_cast<const float4*>(ap + k0 + 4);
      bfrag8 af;
      af[0] = (short)f2bf(a0.x); af[1] = (short)f2bf(a0.y);
      af[2] = (short)f2bf(a0.z); af[3] = (short)f2bf(a0.w);
      af[4] = (short)f2bf(a1.x); af[5] = (short)f2bf(a1.y);
      af[6] = (short)f2bf(a1.z); af[7] = (short)f2bf(a1.w);
#pragma unroll
      for (int tt = 0; tt < 4; ++tt) {
        const bfrag8 bf = *reinterpret_cast<const bfrag8*>(
            bp + (size_t)tt * 32 * 512 + k0);
        // swapped operands -> lane dim = s row (coalesced V^T stores)
        acc[tt] = __builtin_amdgcn_mfma_f32_32x32x16_bf16(bf, af, acc[tt], 0, 0, 0);
      }
    }

    const int s = r0 + lo;
    const int bb = s >> 11, sl = s & (S_LEN - 1);
#pragma unroll
    for (int tt = 0; tt < 4; ++tt) {
#pragma unroll
      for (int r = 0; r < 16; ++r) {
        const int c = ct0 + tt * 32 + (r & 3) + 8 * (r >> 2) + 4 * hi;
        vT_bf[((size_t)(bb * 256 + c)) * S_LEN + sl] = f2bf(acc[tt][r] + bv[c]);
      }
    }
  }
}

// ---------------------------------------------------------------------------
// MFMA attention (round-4 structure): block = 32 q rows of one (b,h), 4 waves
// split the key dim; fragments direct from global bf16; XCD-aware swizzle
// (4 consecutive bh per XCD); mask folded into pad dim 12; bf16 x output.
// ---------------------------------------------------------------------------
__global__ __launch_bounds__(256) void attn_mfma(
    const unsigned short* __restrict__ q_bf,
    const unsigned short* __restrict__ k_bf,
    const unsigned short* __restrict__ vT_bf,
    float* __restrict__ p_out, unsigned short* __restrict__ x_bf)
{
  const int id = blockIdx.x + blockIdx.y * 64;       // 0..2047
  const int xcd = id & 7, jj = id >> 3;
  const int bh = 4 * xcd + (jj >> 6);                // 4 bh per XCD
  const int q0 = (jj & 63) * 32;
  const int b = bh >> 3, h = bh & 7;
  const int t = threadIdx.x, w = t >> 6, lane = t & 63;
  const int lo = lane & 31, hi = lane >> 5;

  __shared__ float red_lds[4][32];
  __shared__ __align__(16) char smbuf[4 * 64 * 20 * 4];  // p[4][32][36] | xr[4][64][20]
  float (*p_lds)[32][36] = reinterpret_cast<float (*)[32][36]>(smbuf);
  float (*xr)[64][20]    = reinterpret_cast<float (*)[64][20]>(smbuf);

  const bfrag8 qf = *reinterpret_cast<const bfrag8*>(
      q_bf + (size_t)(b * S_LEN + q0 + lo) * 128 + h * 16 + hi * 8);
  const unsigned short* kbase = k_bf + (size_t)b * S_LEN * 128 + h * 16 + hi * 8;

  f32x16 zc;
#pragma unroll
  for (int r = 0; r < 16; ++r) zc[r] = 0.f;

  // ---------------- pass 1: row sums ----------------
  float sum = 0.f;
  for (int ch = w * 64; ch < S_LEN; ch += 256) {
#pragma unroll
    for (int T = 0; T < 2; ++T) {
      const bfrag8 kf = *reinterpret_cast<const bfrag8*>(
          kbase + (size_t)(ch + T * 32 + lo) * 128);
      const f32x16 sc = __builtin_amdgcn_mfma_f32_32x32x16_bf16(kf, qf, zc, 0, 0, 0);
#pragma unroll
      for (int r = 0; r < 16; ++r) sum += __expf(sc[r]);
    }
  }
  sum += __shfl_xor(sum, 32);
  if (hi == 0) red_lds[w][lo] = sum;
  __syncthreads();
  const float inv = 1.0f /
      (red_lds[0][lo] + red_lds[1][lo] + red_lds[2][lo] + red_lds[3][lo]);

  // ---------------- pass 2: p write + PV ----------------
  f32x16 xacc;
#pragma unroll
  for (int r = 0; r < 16; ++r) xacc[r] = 0.f;

  const unsigned short* vbase = vT_bf + (size_t)(b * 256 + h * 32 + lo) * S_LEN;
  float* pg0 = p_out + (size_t)bh * S_LEN * S_LEN + (size_t)q0 * S_LEN;

  for (int ch = w * 64; ch < S_LEN; ch += 256) {
#pragma unroll
    for (int T = 0; T < 2; ++T) {
      const bfrag8 kf = *reinterpret_cast<const bfrag8*>(
          kbase + (size_t)(ch + T * 32 + lo) * 128);
      const f32x16 sc = __builtin_amdgcn_mfma_f32_32x32x16_bf16(kf, qf, zc, 0, 0, 0);

#pragma unroll
      for (int qd = 0; qd < 4; ++qd) {
        f32x4 ev;
        ev.x = __expf(sc[qd * 4 + 0]) * inv;
        ev.y = __expf(sc[qd * 4 + 1]) * inv;
        ev.z = __expf(sc[qd * 4 + 2]) * inv;
        ev.w = __expf(sc[qd * 4 + 3]) * inv;
        *reinterpret_cast<f32x4*>(&p_lds[w][lo][qd * 8 + hi * 4]) = ev;
      }

      float* pg = pg0 + ch + T * 32;
#pragma unroll
      for (int i = 0; i < 4; ++i) {
        const int row = i * 8 + (lane >> 3);
        const int k4  = (lane & 7) * 4;
        const f32x4 pv = *reinterpret_cast<const f32x4*>(&p_lds[w][row][k4]);
        __builtin_nontemporal_store(pv,
            reinterpret_cast<f32x4*>(pg + (size_t)row * S_LEN + k4));
      }

#pragma unroll
      for (int m = 0; m < 2; ++m) {
        const f32x4 pa = *reinterpret_cast<const f32x4*>(&p_lds[w][lo][m * 16 + hi * 8]);
        const f32x4 pb = *reinterpret_cast<const f32x4*>(&p_lds[w][lo][m * 16 + hi * 8 + 4]);
        bfrag8 af;
        af[0] = (short)f2bf(pa.x); af[1] = (short)f2bf(pa.y);
        af[2] = (short)f2bf(pa.z); af[3] = (short)f2bf(pa.w);
        af[4] = (short)f2bf(pb.x); af[5] = (short)f2bf(pb.y);
        af[6] = (short)f2bf(pb.z); af[7] = (short)f2bf(pb.w);
        const bfrag8 vf = *reinterpret_cast<const bfrag8*>(
            vbase + ch + T * 32 + m * 16 + hi * 8);
        xacc = __builtin_amdgcn_mfma_f32_32x32x16_bf16(af, vf, xacc, 0, 0, 0);
      }
    }
  }

  // ---------------- cross-wave X reduce + bf16 write ----------------
  __syncthreads();
#pragma unroll
  for (int r = 0; r < 16; r += 4) {
    f32x4 v4; v4.x = xacc[r]; v4.y = xacc[r + 1]; v4.z = xacc[r + 2]; v4.w = xacc[r + 3];
    *reinterpret_cast<f32x4*>(&xr[w][lane][r]) = v4;
  }
  __syncthreads();
  unsigned short* xw = x_bf + (size_t)(b * S_LEN + q0) * 256 + h * 32 + lo;
#pragma unroll
  for (int j = 0; j < 4; ++j) {
    const int rr = w * 4 + j;
    const float xs = xr[0][lane][rr] + xr[1][lane][rr]
                   + xr[2][lane][rr] + xr[3][lane][rr];
    const int row = j + 8 * w + 4 * hi;
    xw[(size_t)row * 256] = f2bf(xs);
  }
}

// ---------------------------------------------------------------------------
// Output projection: C[8192,512] = x_bf[8192,256] @ WxT^T + bx, fp32 out.
// 256 blocks, XCD-swizzled (8 row-panels per XCD, 4 col-tile-groups re-hit L2).
// ---------------------------------------------------------------------------
__global__ __launch_bounds__(256) void out_proj(
    const unsigned short* __restrict__ x_bf,
    const unsigned short* __restrict__ wxT,
    const float* __restrict__ bx, float* __restrict__ out)
{
  const int id = blockIdx.x;
  const int xcd = id & 7, j = id >> 3;          // j 0..31
  const int bxl = j & 7, by = j >> 3;           // by 0..3
  const int bx_ = xcd * 8 + bxl;
  const int t = threadIdx.x, w = t >> 6, lane = t & 63;
  const int lo = lane & 31, hi = lane >> 5;
  const int r0 = bx_ * 128 + 32 * w;
  const int c00 = by * 128;

  const unsigned short* ap = x_bf + (size_t)(r0 + lo) * 256 + hi * 8;
  const unsigned short* bp = wxT + (size_t)(c00 + lo) * 256 + hi * 8;

  f32x16 acc[4];
#pragma unroll
  for (int tt = 0; tt < 4; ++tt)
#pragma unroll
    for (int r = 0; r < 16; ++r) acc[tt][r] = 0.f;

  for (int k0 = 0; k0 < 256; k0 += 16) {
    const bfrag8 af = *reinterpret_cast<const bfrag8*>(ap + k0);
#pragma unroll
    for (int tt = 0; tt < 4; ++tt) {
      const bfrag8 bf = *reinterpret_cast<const bfrag8*>(
          bp + (size_t)tt * 32 * 256 + k0);
      acc[tt] = __builtin_amdgcn_mfma_f32_32x32x16_bf16(af, bf, acc[tt], 0, 0, 0);
    }
  }

#pragma unroll
  for (int tt = 0; tt < 4; ++tt) {
    const int c = c00 + tt * 32 + lo;
    const float bc = bx[c];
#pragma unroll
    for (int r = 0; r < 16; ++r) {
      const int grow = r0 + (r & 3) + 8 * (r >> 2) + 4 * hi;
      out[(size_t)grow * 512 + c] = acc[tt][r] + bc;
    }
  }
}

// ---------------------------------------------------------------------------
extern "C" void kernel_launch(void* const* d_in, const int* in_sizes, int n_in,
                              void* d_out, int out_size, void* d_ws, size_t ws_size,
                              hipStream_t stream) {
  const float* query = (const float*)d_in[0];
  const float* key_  = (const float*)d_in[1];
  const float* value = (const float*)d_in[2];
  const int*   mask  = (const int*)d_in[3];
  const float* Wq = (const float*)d_in[4];
  const float* bq = (const float*)d_in[5];
  const float* Wk = (const float*)d_in[6];
  const float* bk = (const float*)d_in[7];
  const float* Wv = (const float*)d_in[8];
  const float* bv = (const float*)d_in[9];
  const float* Wx = (const float*)d_in[10];
  const float* bx = (const float*)d_in[11];

  const int M = NB * S_LEN;                  // 8192
  float* out_x = (float*)d_out;              // [4,2048,512]
  float* out_p = out_x + (size_t)M * 512;    // [4,8,2048,2048]

  unsigned short* wqT  = (unsigned short*)d_ws;             // 96*512
  unsigned short* wkT  = wqT + 49152;                       // 96*512
  unsigned short* wvT  = wkT + 49152;                       // 256*512
  unsigned short* wxT  = wvT + 131072;                      // 512*256
  unsigned short* q_bf = wxT + 131072;                      // 8192*128
  unsigned short* k_bf = q_bf + (size_t)M * 128;            // 8192*128
  unsigned short* vT_bf = k_bf + (size_t)M * 128;           // 4*256*2048
  unsigned short* x_bf = vT_bf + (size_t)NB * 256 * S_LEN;  // 8192*256

  const float qscale = 0.28867513459481287f;  // 1/sqrt(12)

  transpose_w<<<1408, 256, 0, stream>>>(Wq, Wk, Wv, Wx, wqT, wkT, wvT, wxT);

  proj_qkv<<<512, 256, 0, stream>>>(
      query, key_, value, mask, wqT, wkT, wvT, bq, bk, bv,
      q_bf, k_bf, vT_bf, qscale);

  attn_mfma<<<dim3(S_LEN / 32, NB * NH), 256, 0, stream>>>(
      q_bf, k_bf, vT_bf, out_p, x_bf);

  out_proj<<<256, 256, 0, stream>>>(x_bf, wxT, bx, out_x);
}

// Round 6
// 169.123 us; speedup vs baseline: 4.4025x; 1.0068x over previous
//
#include <hip/hip_runtime.h>
#include <math.h>

#define S_LEN 2048
#define NB 4
#define NH 8

typedef short bfrag8 __attribute__((ext_vector_type(8)));
typedef float f32x16 __attribute__((ext_vector_type(16)));
typedef float f32x4 __attribute__((ext_vector_type(4)));

#if __has_builtin(__builtin_amdgcn_exp2f)
#define EXP2(x) __builtin_amdgcn_exp2f(x)
#else
#define EXP2(x) exp2f(x)
#endif

__device__ __forceinline__ unsigned short f2bf(float x) {
  union { float f; unsigned u; } v; v.f = x;
  unsigned r = v.u + 0x7FFFu + ((v.u >> 16) & 1u);
  return (unsigned short)(r >> 16);
}

// ---------------------------------------------------------------------------
// Transpose weights to bf16 W^T (tiny): WqT/WkT[96][512], WvT[256][512],
// WxT[512][256].
// ---------------------------------------------------------------------------
__global__ __launch_bounds__(256) void transpose_w(
    const float* __restrict__ Wq, const float* __restrict__ Wk,
    const float* __restrict__ Wv, const float* __restrict__ Wx,
    unsigned short* __restrict__ wqT, unsigned short* __restrict__ wkT,
    unsigned short* __restrict__ wvT, unsigned short* __restrict__ wxT)
{
  int i = blockIdx.x * 256 + threadIdx.x;
  if (i < 49152) {
    const int n = i / 512, kk = i % 512;
    wqT[i] = f2bf(Wq[(size_t)kk * 96 + n]);
  } else if (i < 98304) {
    i -= 49152; const int n = i / 512, kk = i % 512;
    wkT[i] = f2bf(Wk[(size_t)kk * 96 + n]);
  } else if (i < 229376) {
    i -= 98304; const int n = i / 512, kk = i % 512;
    wvT[i] = f2bf(Wv[(size_t)kk * 256 + n]);
  } else if (i < 360448) {
    i -= 229376; const int n = i / 256, kk = i % 256;
    wxT[i] = f2bf(Wx[(size_t)kk * 512 + n]);
  }
}

// ---------------------------------------------------------------------------
// Fused QKV projection, LDS-free MFMA, fp32 A loaded directly (cast fused),
// pad/mask fill fused into epilogue. Grid: 512 blocks, XCD-swizzled.
// ys 0..2: q col-tile ys     -> q_bf (padded-head layout, * qscale)
// ys 3..5: k col-tile ys-3   -> k_bf (padded-head layout, mask in pad slot)
// ys 6..7: v, 4 col-tiles    -> vT_bf [b][256][2048] (swapped-operand MFMA)
// ---------------------------------------------------------------------------
__global__ __launch_bounds__(256) void proj_qkv(
    const float* __restrict__ query, const float* __restrict__ key_,
    const float* __restrict__ value, const int* __restrict__ mask,
    const unsigned short* __restrict__ wqT, const unsigned short* __restrict__ wkT,
    const unsigned short* __restrict__ wvT,
    const float* __restrict__ bq, const float* __restrict__ bk,
    const float* __restrict__ bv,
    unsigned short* __restrict__ q_bf, unsigned short* __restrict__ k_bf,
    unsigned short* __restrict__ vT_bf, float qscale)
{
  const int id = blockIdx.x;
  const int xcd = id & 7, j = id >> 3;
  const int bxl = j & 7, ys = j >> 3;
  const int bx = xcd * 8 + bxl;
  const int t = threadIdx.x, w = t >> 6, lane = t & 63;
  const int lo = lane & 31, hi = lane >> 5;
  const int r0 = bx * 128 + 32 * w;

  if (ys < 6) {
    const bool isq = (ys < 3);
    const float* A = isq ? query : key_;
    const unsigned short* BT = isq ? wqT : wkT;
    const float* bias = isq ? bq : bk;
    unsigned short* Cb = isq ? q_bf : k_bf;
    const float osc = isq ? qscale : 1.0f;
    const int c0 = (isq ? ys : ys - 3) * 32;

    const float* ap = A + (size_t)(r0 + lo) * 512 + hi * 8;
    const unsigned short* bp = BT + (size_t)(c0 + lo) * 512 + hi * 8;

    f32x16 acc;
#pragma unroll
    for (int r = 0; r < 16; ++r) acc[r] = 0.f;

    for (int k0 = 0; k0 < 512; k0 += 16) {
      const float4 a0 = *reinterpret_cast<const float4*>(ap + k0);
      const float4 a1 = *reinterpret_cast<const float4*>(ap + k0 + 4);
      bfrag8 af;
      af[0] = (short)f2bf(a0.x); af[1] = (short)f2bf(a0.y);
      af[2] = (short)f2bf(a0.z); af[3] = (short)f2bf(a0.w);
      af[4] = (short)f2bf(a1.x); af[5] = (short)f2bf(a1.y);
      af[6] = (short)f2bf(a1.z); af[7] = (short)f2bf(a1.w);
      const bfrag8 bf = *reinterpret_cast<const bfrag8*>(bp + k0);
      acc = __builtin_amdgcn_mfma_f32_32x32x16_bf16(af, bf, acc, 0, 0, 0);
    }

    const int c = c0 + lo;
    const int off = (c / 12) * 16 + (c % 12);
    const float bc = bias[c];
#pragma unroll
    for (int r = 0; r < 16; ++r) {
      const int grow = r0 + (r & 3) + 8 * (r >> 2) + 4 * hi;
      Cb[(size_t)grow * 128 + off] = f2bf((acc[r] + bc) * osc);
    }
    // fused pad fill: one lane per head per tile (c multiple of 12)
    if ((c % 12) == 0) {
      const int hh = c / 12;
#pragma unroll
      for (int r = 0; r < 16; ++r) {
        const int grow = r0 + (r & 3) + 8 * (r >> 2) + 4 * hi;
        ushort4 pv;
        pv.x = isq ? (unsigned short)0x3F80
                   : ((mask[grow] != 0) ? (unsigned short)0
                                        : (unsigned short)0xCE6E);
        pv.y = 0; pv.z = 0; pv.w = 0;
        *reinterpret_cast<ushort4*>(Cb + (size_t)grow * 128 + hh * 16 + 12) = pv;
      }
    }
  } else {
    const int ct0 = (ys - 6) * 128;
    const float* ap = value + (size_t)(r0 + lo) * 512 + hi * 8;
    const unsigned short* bp = wvT + (size_t)(ct0 + lo) * 512 + hi * 8;

    f32x16 acc[4];
#pragma unroll
    for (int tt = 0; tt < 4; ++tt)
#pragma unroll
      for (int r = 0; r < 16; ++r) acc[tt][r] = 0.f;

    for (int k0 = 0; k0 < 512; k0 += 16) {
      const float4 a0 = *reinterpret_cast<const float4*>(ap + k0);
      const float4 a1 = *reinterpret_cast<const float4*>(ap + k0 + 4);
      bfrag8 af;
      af[0] = (short)f2bf(a0.x); af[1] = (short)f2bf(a0.y);
      af[2] = (short)f2bf(a0.z); af[3] = (short)f2bf(a0.w);
      af[4] = (short)f2bf(a1.x); af[5] = (short)f2bf(a1.y);
      af[6] = (short)f2bf(a1.z); af[7] = (short)f2bf(a1.w);
#pragma unroll
      for (int tt = 0; tt < 4; ++tt) {
        const bfrag8 bf = *reinterpret_cast<const bfrag8*>(
            bp + (size_t)tt * 32 * 512 + k0);
        acc[tt] = __builtin_amdgcn_mfma_f32_32x32x16_bf16(bf, af, acc[tt], 0, 0, 0);
      }
    }

    const int s = r0 + lo;
    const int bb = s >> 11, sl = s & (S_LEN - 1);
#pragma unroll
    for (int tt = 0; tt < 4; ++tt) {
#pragma unroll
      for (int r = 0; r < 16; ++r) {
        const int c = ct0 + tt * 32 + (r & 3) + 8 * (r >> 2) + 4 * hi;
        vT_bf[((size_t)(bb * 256 + c)) * S_LEN + sl] = f2bf(acc[tt][r] + bv[c]);
      }
    }
  }
}

// ---------------------------------------------------------------------------
// MFMA attention: block = 32 q rows of one (b,h), 4 waves split the key dim;
// fragments direct from global bf16; XCD swizzle (4 bh per XCD); mask folded
// into pad dim 12. qscale includes log2(e) so softmax uses raw v_exp_f32.
// p stores batched 64-wide (256B contiguous runs per row) via per-wave
// p_lds[32][68] (stride-68: conflict-free at the structural LDS minimum).
// ---------------------------------------------------------------------------
__global__ __launch_bounds__(256) void attn_mfma(
    const unsigned short* __restrict__ q_bf,
    const unsigned short* __restrict__ k_bf,
    const unsigned short* __restrict__ vT_bf,
    float* __restrict__ p_out, unsigned short* __restrict__ x_bf)
{
  const int id = blockIdx.x + blockIdx.y * 64;       // 0..2047
  const int xcd = id & 7, jj = id >> 3;
  const int bh = 4 * xcd + (jj >> 6);                // 4 bh per XCD
  const int q0 = (jj & 63) * 32;
  const int b = bh >> 3, h = bh & 7;
  const int t = threadIdx.x, w = t >> 6, lane = t & 63;
  const int lo = lane & 31, hi = lane >> 5;

  __shared__ float red_lds[4][32];
  __shared__ __align__(16) char smbuf[4 * 32 * 68 * 4];  // p[4][32][68] | xr[4][64][20]
  float (*p_lds)[32][68] = reinterpret_cast<float (*)[32][68]>(smbuf);
  float (*xr)[64][20]    = reinterpret_cast<float (*)[64][20]>(smbuf);

  const bfrag8 qf = *reinterpret_cast<const bfrag8*>(
      q_bf + (size_t)(b * S_LEN + q0 + lo) * 128 + h * 16 + hi * 8);
  const unsigned short* kbase = k_bf + (size_t)b * S_LEN * 128 + h * 16 + hi * 8;

  f32x16 zc;
#pragma unroll
  for (int r = 0; r < 16; ++r) zc[r] = 0.f;

  // ---------------- pass 1: row sums ----------------
  float sum = 0.f;
  for (int ch = w * 64; ch < S_LEN; ch += 256) {
#pragma unroll
    for (int T = 0; T < 2; ++T) {
      const bfrag8 kf = *reinterpret_cast<const bfrag8*>(
          kbase + (size_t)(ch + T * 32 + lo) * 128);
      const f32x16 sc = __builtin_amdgcn_mfma_f32_32x32x16_bf16(kf, qf, zc, 0, 0, 0);
#pragma unroll
      for (int r = 0; r < 16; ++r) sum += EXP2(sc[r]);
    }
  }
  sum += __shfl_xor(sum, 32);
  if (hi == 0) red_lds[w][lo] = sum;
  __syncthreads();
  const float inv = 1.0f /
      (red_lds[0][lo] + red_lds[1][lo] + red_lds[2][lo] + red_lds[3][lo]);

  // ---------------- pass 2: p write + PV ----------------
  f32x16 xacc;
#pragma unroll
  for (int r = 0; r < 16; ++r) xacc[r] = 0.f;

  const unsigned short* vbase = vT_bf + (size_t)(b * 256 + h * 32 + lo) * S_LEN;
  float* pg0 = p_out + (size_t)bh * S_LEN * S_LEN + (size_t)q0 * S_LEN;

  for (int ch = w * 64; ch < S_LEN; ch += 256) {
#pragma unroll
    for (int T = 0; T < 2; ++T) {
      const bfrag8 kf = *reinterpret_cast<const bfrag8*>(
          kbase + (size_t)(ch + T * 32 + lo) * 128);
      const f32x16 sc = __builtin_amdgcn_mfma_f32_32x32x16_bf16(kf, qf, zc, 0, 0, 0);

#pragma unroll
      for (int qd = 0; qd < 4; ++qd) {
        f32x4 ev;
        ev.x = EXP2(sc[qd * 4 + 0]) * inv;
        ev.y = EXP2(sc[qd * 4 + 1]) * inv;
        ev.z = EXP2(sc[qd * 4 + 2]) * inv;
        ev.w = EXP2(sc[qd * 4 + 3]) * inv;
        *reinterpret_cast<f32x4*>(&p_lds[w][lo][T * 32 + qd * 8 + hi * 4]) = ev;
      }

#pragma unroll
      for (int m = 0; m < 2; ++m) {
        const f32x4 pa = *reinterpret_cast<const f32x4*>(
            &p_lds[w][lo][T * 32 + m * 16 + hi * 8]);
        const f32x4 pb = *reinterpret_cast<const f32x4*>(
            &p_lds[w][lo][T * 32 + m * 16 + hi * 8 + 4]);
        bfrag8 af;
        af[0] = (short)f2bf(pa.x); af[1] = (short)f2bf(pa.y);
        af[2] = (short)f2bf(pa.z); af[3] = (short)f2bf(pa.w);
        af[4] = (short)f2bf(pb.x); af[5] = (short)f2bf(pb.y);
        af[6] = (short)f2bf(pb.z); af[7] = (short)f2bf(pb.w);
        const bfrag8 vf = *reinterpret_cast<const bfrag8*>(
            vbase + ch + T * 32 + m * 16 + hi * 8);
        xacc = __builtin_amdgcn_mfma_f32_32x32x16_bf16(af, vf, xacc, 0, 0, 0);
      }
    }

    // 64-wide (256B per row) nontemporal p stores: 4 rows x 64 keys / instr
    float* pg = pg0 + ch;
#pragma unroll
    for (int i = 0; i < 8; ++i) {
      const int row = i * 4 + (lane >> 4);
      const int k4  = (lane & 15) * 4;
      const f32x4 pv = *reinterpret_cast<const f32x4*>(&p_lds[w][row][k4]);
      __builtin_nontemporal_store(pv,
          reinterpret_cast<f32x4*>(pg + (size_t)row * S_LEN + k4));
    }
  }

  // ---------------- cross-wave X reduce + bf16 write ----------------
  __syncthreads();
#pragma unroll
  for (int r = 0; r < 16; r += 4) {
    f32x4 v4; v4.x = xacc[r]; v4.y = xacc[r + 1]; v4.z = xacc[r + 2]; v4.w = xacc[r + 3];
    *reinterpret_cast<f32x4*>(&xr[w][lane][r]) = v4;
  }
  __syncthreads();
  unsigned short* xw = x_bf + (size_t)(b * S_LEN + q0) * 256 + h * 32 + lo;
#pragma unroll
  for (int j = 0; j < 4; ++j) {
    const int rr = w * 4 + j;
    const float xs = xr[0][lane][rr] + xr[1][lane][rr]
                   + xr[2][lane][rr] + xr[3][lane][rr];
    const int row = j + 8 * w + 4 * hi;
    xw[(size_t)row * 256] = f2bf(xs);
  }
}

// ---------------------------------------------------------------------------
// Output projection: C[8192,512] = x_bf[8192,256] @ WxT^T + bx, fp32 out.
// 256 blocks, XCD-swizzled.
// ---------------------------------------------------------------------------
__global__ __launch_bounds__(256) void out_proj(
    const unsigned short* __restrict__ x_bf,
    const unsigned short* __restrict__ wxT,
    const float* __restrict__ bx, float* __restrict__ out)
{
  const int id = blockIdx.x;
  const int xcd = id & 7, j = id >> 3;
  const int bxl = j & 7, by = j >> 3;
  const int bx_ = xcd * 8 + bxl;
  const int t = threadIdx.x, w = t >> 6, lane = t & 63;
  const int lo = lane & 31, hi = lane >> 5;
  const int r0 = bx_ * 128 + 32 * w;
  const int c00 = by * 128;

  const unsigned short* ap = x_bf + (size_t)(r0 + lo) * 256 + hi * 8;
  const unsigned short* bp = wxT + (size_t)(c00 + lo) * 256 + hi * 8;

  f32x16 acc[4];
#pragma unroll
  for (int tt = 0; tt < 4; ++tt)
#pragma unroll
    for (int r = 0; r < 16; ++r) acc[tt][r] = 0.f;

  for (int k0 = 0; k0 < 256; k0 += 16) {
    const bfrag8 af = *reinterpret_cast<const bfrag8*>(ap + k0);
#pragma unroll
    for (int tt = 0; tt < 4; ++tt) {
      const bfrag8 bf = *reinterpret_cast<const bfrag8*>(
          bp + (size_t)tt * 32 * 256 + k0);
      acc[tt] = __builtin_amdgcn_mfma_f32_32x32x16_bf16(af, bf, acc[tt], 0, 0, 0);
    }
  }

#pragma unroll
  for (int tt = 0; tt < 4; ++tt) {
    const int c = c00 + tt * 32 + lo;
    const float bc = bx[c];
#pragma unroll
    for (int r = 0; r < 16; ++r) {
      const int grow = r0 + (r & 3) + 8 * (r >> 2) + 4 * hi;
      out[(size_t)grow * 512 + c] = acc[tt][r] + bc;
    }
  }
}

// ---------------------------------------------------------------------------
extern "C" void kernel_launch(void* const* d_in, const int* in_sizes, int n_in,
                              void* d_out, int out_size, void* d_ws, size_t ws_size,
                              hipStream_t stream) {
  const float* query = (const float*)d_in[0];
  const float* key_  = (const float*)d_in[1];
  const float* value = (const float*)d_in[2];
  const int*   mask  = (const int*)d_in[3];
  const float* Wq = (const float*)d_in[4];
  const float* bq = (const float*)d_in[5];
  const float* Wk = (const float*)d_in[6];
  const float* bk = (const float*)d_in[7];
  const float* Wv = (const float*)d_in[8];
  const float* bv = (const float*)d_in[9];
  const float* Wx = (const float*)d_in[10];
  const float* bx = (const float*)d_in[11];

  const int M = NB * S_LEN;                  // 8192
  float* out_x = (float*)d_out;              // [4,2048,512]
  float* out_p = out_x + (size_t)M * 512;    // [4,8,2048,2048]

  unsigned short* wqT  = (unsigned short*)d_ws;             // 96*512
  unsigned short* wkT  = wqT + 49152;                       // 96*512
  unsigned short* wvT  = wkT + 49152;                       // 256*512
  unsigned short* wxT  = wvT + 131072;                      // 512*256
  unsigned short* q_bf = wxT + 131072;                      // 8192*128
  unsigned short* k_bf = q_bf + (size_t)M * 128;            // 8192*128
  unsigned short* vT_bf = k_bf + (size_t)M * 128;           // 4*256*2048
  unsigned short* x_bf = vT_bf + (size_t)NB * 256 * S_LEN;  // 8192*256

  // 1/sqrt(12) * log2(e): scores come out of the MFMA in log2 units, so
  // softmax needs only raw v_exp_f32 (exp2), no per-element multiply.
  const float qscale = 1.4426950408889634f / sqrtf(12.0f);

  transpose_w<<<1408, 256, 0, stream>>>(Wq, Wk, Wv, Wx, wqT, wkT, wvT, wxT);

  proj_qkv<<<512, 256, 0, stream>>>(
      query, key_, value, mask, wqT, wkT, wvT, bq, bk, bv,
      q_bf, k_bf, vT_bf, qscale);

  attn_mfma<<<dim3(S_LEN / 32, NB * NH), 256, 0, stream>>>(
      q_bf, k_bf, vT_bf, out_p, x_bf);

  out_proj<<<256, 256, 0, stream>>>(x_bf, wxT, bx, out_x);
}

// Round 7
// 169.080 us; speedup vs baseline: 4.4036x; 1.0003x over previous
//
#include <hip/hip_runtime.h>
#include <math.h>

#define S_LEN 2048
#define NB 4
#define NH 8

typedef short bfrag8 __attribute__((ext_vector_type(8)));
typedef float f32x16 __attribute__((ext_vector_type(16)));
typedef float f32x4 __attribute__((ext_vector_type(4)));

#if __has_builtin(__builtin_amdgcn_exp2f)
#define EXP2(x) __builtin_amdgcn_exp2f(x)
#else
#define EXP2(x) exp2f(x)
#endif

__device__ __forceinline__ unsigned short f2bf(float x) {
  union { float f; unsigned u; } v; v.f = x;
  unsigned r = v.u + 0x7FFFu + ((v.u >> 16) & 1u);
  return (unsigned short)(r >> 16);
}

// ---------------------------------------------------------------------------
// Transpose weights to bf16 W^T (tiny): WqT/WkT[96][512], WvT[256][512],
// WxT[512][256].
// ---------------------------------------------------------------------------
__global__ __launch_bounds__(256) void transpose_w(
    const float* __restrict__ Wq, const float* __restrict__ Wk,
    const float* __restrict__ Wv, const float* __restrict__ Wx,
    unsigned short* __restrict__ wqT, unsigned short* __restrict__ wkT,
    unsigned short* __restrict__ wvT, unsigned short* __restrict__ wxT)
{
  int i = blockIdx.x * 256 + threadIdx.x;
  if (i < 49152) {
    const int n = i / 512, kk = i % 512;
    wqT[i] = f2bf(Wq[(size_t)kk * 96 + n]);
  } else if (i < 98304) {
    i -= 49152; const int n = i / 512, kk = i % 512;
    wkT[i] = f2bf(Wk[(size_t)kk * 96 + n]);
  } else if (i < 229376) {
    i -= 98304; const int n = i / 512, kk = i % 512;
    wvT[i] = f2bf(Wv[(size_t)kk * 256 + n]);
  } else if (i < 360448) {
    i -= 229376; const int n = i / 256, kk = i % 256;
    wxT[i] = f2bf(Wx[(size_t)kk * 512 + n]);
  }
}

// ---------------------------------------------------------------------------
// Fused QKV projection, LDS-free MFMA, fp32 A loaded directly (cast fused),
// pad/mask fill fused into epilogue. Grid: 512 blocks, XCD-swizzled.
// ys 0..2: q col-tile ys     -> q_bf (padded-head layout, * qscale)
// ys 3..5: k col-tile ys-3   -> k_bf (padded-head layout, mask in pad slot)
// ys 6..7: v, 4 col-tiles    -> vT_bf [b][256][2048] (swapped-operand MFMA)
// ---------------------------------------------------------------------------
__global__ __launch_bounds__(256) void proj_qkv(
    const float* __restrict__ query, const float* __restrict__ key_,
    const float* __restrict__ value, const int* __restrict__ mask,
    const unsigned short* __restrict__ wqT, const unsigned short* __restrict__ wkT,
    const unsigned short* __restrict__ wvT,
    const float* __restrict__ bq, const float* __restrict__ bk,
    const float* __restrict__ bv,
    unsigned short* __restrict__ q_bf, unsigned short* __restrict__ k_bf,
    unsigned short* __restrict__ vT_bf, float qscale)
{
  const int id = blockIdx.x;
  const int xcd = id & 7, j = id >> 3;
  const int bxl = j & 7, ys = j >> 3;
  const int bx = xcd * 8 + bxl;
  const int t = threadIdx.x, w = t >> 6, lane = t & 63;
  const int lo = lane & 31, hi = lane >> 5;
  const int r0 = bx * 128 + 32 * w;

  if (ys < 6) {
    const bool isq = (ys < 3);
    const float* A = isq ? query : key_;
    const unsigned short* BT = isq ? wqT : wkT;
    const float* bias = isq ? bq : bk;
    unsigned short* Cb = isq ? q_bf : k_bf;
    const float osc = isq ? qscale : 1.0f;
    const int c0 = (isq ? ys : ys - 3) * 32;

    const float* ap = A + (size_t)(r0 + lo) * 512 + hi * 8;
    const unsigned short* bp = BT + (size_t)(c0 + lo) * 512 + hi * 8;

    f32x16 acc;
#pragma unroll
    for (int r = 0; r < 16; ++r) acc[r] = 0.f;

    for (int k0 = 0; k0 < 512; k0 += 16) {
      const float4 a0 = *reinterpret_cast<const float4*>(ap + k0);
      const float4 a1 = *reinterpret_cast<const float4*>(ap + k0 + 4);
      bfrag8 af;
      af[0] = (short)f2bf(a0.x); af[1] = (short)f2bf(a0.y);
      af[2] = (short)f2bf(a0.z); af[3] = (short)f2bf(a0.w);
      af[4] = (short)f2bf(a1.x); af[5] = (short)f2bf(a1.y);
      af[6] = (short)f2bf(a1.z); af[7] = (short)f2bf(a1.w);
      const bfrag8 bf = *reinterpret_cast<const bfrag8*>(bp + k0);
      acc = __builtin_amdgcn_mfma_f32_32x32x16_bf16(af, bf, acc, 0, 0, 0);
    }

    const int c = c0 + lo;
    const int off = (c / 12) * 16 + (c % 12);
    const float bc = bias[c];
#pragma unroll
    for (int r = 0; r < 16; ++r) {
      const int grow = r0 + (r & 3) + 8 * (r >> 2) + 4 * hi;
      Cb[(size_t)grow * 128 + off] = f2bf((acc[r] + bc) * osc);
    }
    // fused pad fill: one lane per head per tile (c multiple of 12)
    if ((c % 12) == 0) {
      const int hh = c / 12;
#pragma unroll
      for (int r = 0; r < 16; ++r) {
        const int grow = r0 + (r & 3) + 8 * (r >> 2) + 4 * hi;
        ushort4 pv;
        pv.x = isq ? (unsigned short)0x3F80
                   : ((mask[grow] != 0) ? (unsigned short)0
                                        : (unsigned short)0xCE6E);
        pv.y = 0; pv.z = 0; pv.w = 0;
        *reinterpret_cast<ushort4*>(Cb + (size_t)grow * 128 + hh * 16 + 12) = pv;
      }
    }
  } else {
    const int ct0 = (ys - 6) * 128;
    const float* ap = value + (size_t)(r0 + lo) * 512 + hi * 8;
    const unsigned short* bp = wvT + (size_t)(ct0 + lo) * 512 + hi * 8;

    f32x16 acc[4];
#pragma unroll
    for (int tt = 0; tt < 4; ++tt)
#pragma unroll
      for (int r = 0; r < 16; ++r) acc[tt][r] = 0.f;

    for (int k0 = 0; k0 < 512; k0 += 16) {
      const float4 a0 = *reinterpret_cast<const float4*>(ap + k0);
      const float4 a1 = *reinterpret_cast<const float4*>(ap + k0 + 4);
      bfrag8 af;
      af[0] = (short)f2bf(a0.x); af[1] = (short)f2bf(a0.y);
      af[2] = (short)f2bf(a0.z); af[3] = (short)f2bf(a0.w);
      af[4] = (short)f2bf(a1.x); af[5] = (short)f2bf(a1.y);
      af[6] = (short)f2bf(a1.z); af[7] = (short)f2bf(a1.w);
#pragma unroll
      for (int tt = 0; tt < 4; ++tt) {
        const bfrag8 bf = *reinterpret_cast<const bfrag8*>(
            bp + (size_t)tt * 32 * 512 + k0);
        acc[tt] = __builtin_amdgcn_mfma_f32_32x32x16_bf16(bf, af, acc[tt], 0, 0, 0);
      }
    }

    const int s = r0 + lo;
    const int bb = s >> 11, sl = s & (S_LEN - 1);
#pragma unroll
    for (int tt = 0; tt < 4; ++tt) {
#pragma unroll
      for (int r = 0; r < 16; ++r) {
        const int c = ct0 + tt * 32 + (r & 3) + 8 * (r >> 2) + 4 * hi;
        vT_bf[((size_t)(bb * 256 + c)) * S_LEN + sl] = f2bf(acc[tt][r] + bv[c]);
      }
    }
  }
}

// ---------------------------------------------------------------------------
// MFMA attention: block = 32 q rows of one (b,h), 4 waves split the key dim;
// fragments direct from global bf16; XCD swizzle (4 bh per XCD); mask folded
// into pad dim 12. qscale includes log2(e) so softmax uses raw v_exp_f32.
// p stores batched 64-wide (256B contiguous runs per row) via per-wave
// p_lds[32][68] (stride-68: conflict-free at the structural LDS minimum).
// ---------------------------------------------------------------------------
__global__ __launch_bounds__(256) void attn_mfma(
    const unsigned short* __restrict__ q_bf,
    const unsigned short* __restrict__ k_bf,
    const unsigned short* __restrict__ vT_bf,
    float* __restrict__ p_out, unsigned short* __restrict__ x_bf)
{
  const int id = blockIdx.x + blockIdx.y * 64;       // 0..2047
  const int xcd = id & 7, jj = id >> 3;
  const int bh = 4 * xcd + (jj >> 6);                // 4 bh per XCD
  const int q0 = (jj & 63) * 32;
  const int b = bh >> 3, h = bh & 7;
  const int t = threadIdx.x, w = t >> 6, lane = t & 63;
  const int lo = lane & 31, hi = lane >> 5;

  __shared__ float red_lds[4][32];
  __shared__ __align__(16) char smbuf[4 * 32 * 68 * 4];  // p[4][32][68] | xr[4][64][20]
  float (*p_lds)[32][68] = reinterpret_cast<float (*)[32][68]>(smbuf);
  float (*xr)[64][20]    = reinterpret_cast<float (*)[64][20]>(smbuf);

  const bfrag8 qf = *reinterpret_cast<const bfrag8*>(
      q_bf + (size_t)(b * S_LEN + q0 + lo) * 128 + h * 16 + hi * 8);
  const unsigned short* kbase = k_bf + (size_t)b * S_LEN * 128 + h * 16 + hi * 8;

  f32x16 zc;
#pragma unroll
  for (int r = 0; r < 16; ++r) zc[r] = 0.f;

  // ---------------- pass 1: row sums ----------------
  float sum = 0.f;
  for (int ch = w * 64; ch < S_LEN; ch += 256) {
#pragma unroll
    for (int T = 0; T < 2; ++T) {
      const bfrag8 kf = *reinterpret_cast<const bfrag8*>(
          kbase + (size_t)(ch + T * 32 + lo) * 128);
      const f32x16 sc = __builtin_amdgcn_mfma_f32_32x32x16_bf16(kf, qf, zc, 0, 0, 0);
#pragma unroll
      for (int r = 0; r < 16; ++r) sum += EXP2(sc[r]);
    }
  }
  sum += __shfl_xor(sum, 32);
  if (hi == 0) red_lds[w][lo] = sum;
  __syncthreads();
  const float inv = 1.0f /
      (red_lds[0][lo] + red_lds[1][lo] + red_lds[2][lo] + red_lds[3][lo]);

  // ---------------- pass 2: p write + PV ----------------
  f32x16 xacc;
#pragma unroll
  for (int r = 0; r < 16; ++r) xacc[r] = 0.f;

  const unsigned short* vbase = vT_bf + (size_t)(b * 256 + h * 32 + lo) * S_LEN;
  float* pg0 = p_out + (size_t)bh * S_LEN * S_LEN + (size_t)q0 * S_LEN;

  for (int ch = w * 64; ch < S_LEN; ch += 256) {
#pragma unroll
    for (int T = 0; T < 2; ++T) {
      const bfrag8 kf = *reinterpret_cast<const bfrag8*>(
          kbase + (size_t)(ch + T * 32 + lo) * 128);
      const f32x16 sc = __builtin_amdgcn_mfma_f32_32x32x16_bf16(kf, qf, zc, 0, 0, 0);

#pragma unroll
      for (int qd = 0; qd < 4; ++qd) {
        f32x4 ev;
        ev.x = EXP2(sc[qd * 4 + 0]) * inv;
        ev.y = EXP2(sc[qd * 4 + 1]) * inv;
        ev.z = EXP2(sc[qd * 4 + 2]) * inv;
        ev.w = EXP2(sc[qd * 4 + 3]) * inv;
        *reinterpret_cast<f32x4*>(&p_lds[w][lo][T * 32 + qd * 8 + hi * 4]) = ev;
      }

#pragma unroll
      for (int m = 0; m < 2; ++m) {
        const f32x4 pa = *reinterpret_cast<const f32x4*>(
            &p_lds[w][lo][T * 32 + m * 16 + hi * 8]);
        const f32x4 pb = *reinterpret_cast<const f32x4*>(
            &p_lds[w][lo][T * 32 + m * 16 + hi * 8 + 4]);
        bfrag8 af;
        af[0] = (short)f2bf(pa.x); af[1] = (short)f2bf(pa.y);
        af[2] = (short)f2bf(pa.z); af[3] = (short)f2bf(pa.w);
        af[4] = (short)f2bf(pb.x); af[5] = (short)f2bf(pb.y);
        af[6] = (short)f2bf(pb.z); af[7] = (short)f2bf(pb.w);
        const bfrag8 vf = *reinterpret_cast<const bfrag8*>(
            vbase + ch + T * 32 + m * 16 + hi * 8);
        xacc = __builtin_amdgcn_mfma_f32_32x32x16_bf16(af, vf, xacc, 0, 0, 0);
      }
    }

    // 64-wide (256B per row) nontemporal p stores: 4 rows x 64 keys / instr
    float* pg = pg0 + ch;
#pragma unroll
    for (int i = 0; i < 8; ++i) {
      const int row = i * 4 + (lane >> 4);
      const int k4  = (lane & 15) * 4;
      const f32x4 pv = *reinterpret_cast<const f32x4*>(&p_lds[w][row][k4]);
      __builtin_nontemporal_store(pv,
          reinterpret_cast<f32x4*>(pg + (size_t)row * S_LEN + k4));
    }
  }

  // ---------------- cross-wave X reduce + bf16 write ----------------
  __syncthreads();
#pragma unroll
  for (int r = 0; r < 16; r += 4) {
    f32x4 v4; v4.x = xacc[r]; v4.y = xacc[r + 1]; v4.z = xacc[r + 2]; v4.w = xacc[r + 3];
    *reinterpret_cast<f32x4*>(&xr[w][lane][r]) = v4;
  }
  __syncthreads();
  unsigned short* xw = x_bf + (size_t)(b * S_LEN + q0) * 256 + h * 32 + lo;
#pragma unroll
  for (int j = 0; j < 4; ++j) {
    const int rr = w * 4 + j;
    const float xs = xr[0][lane][rr] + xr[1][lane][rr]
                   + xr[2][lane][rr] + xr[3][lane][rr];
    const int row = j + 8 * w + 4 * hi;
    xw[(size_t)row * 256] = f2bf(xs);
  }
}

// ---------------------------------------------------------------------------
// Output projection: C[8192,512] = x_bf[8192,256] @ WxT^T + bx, fp32 out.
// 256 blocks, XCD-swizzled.
// ---------------------------------------------------------------------------
__global__ __launch_bounds__(256) void out_proj(
    const unsigned short* __restrict__ x_bf,
    const unsigned short* __restrict__ wxT,
    const float* __restrict__ bx, float* __restrict__ out)
{
  const int id = blockIdx.x;
  const int xcd = id & 7, j = id >> 3;
  const int bxl = j & 7, by = j >> 3;
  const int bx_ = xcd * 8 + bxl;
  const int t = threadIdx.x, w = t >> 6, lane = t & 63;
  const int lo = lane & 31, hi = lane >> 5;
  const int r0 = bx_ * 128 + 32 * w;
  const int c00 = by * 128;

  const unsigned short* ap = x_bf + (size_t)(r0 + lo) * 256 + hi * 8;
  const unsigned short* bp = wxT + (size_t)(c00 + lo) * 256 + hi * 8;

  f32x16 acc[4];
#pragma unroll
  for (int tt = 0; tt < 4; ++tt)
#pragma unroll
    for (int r = 0; r < 16; ++r) acc[tt][r] = 0.f;

  for (int k0 = 0; k0 < 256; k0 += 16) {
    const bfrag8 af = *reinterpret_cast<const bfrag8*>(ap + k0);
#pragma unroll
    for (int tt = 0; tt < 4; ++tt) {
      const bfrag8 bf = *reinterpret_cast<const bfrag8*>(
          bp + (size_t)tt * 32 * 256 + k0);
      acc[tt] = __builtin_amdgcn_mfma_f32_32x32x16_bf16(af, bf, acc[tt], 0, 0, 0);
    }
  }

#pragma unroll
  for (int tt = 0; tt < 4; ++tt) {
    const int c = c00 + tt * 32 + lo;
    const float bc = bx[c];
#pragma unroll
    for (int r = 0; r < 16; ++r) {
      const int grow = r0 + (r & 3) + 8 * (r >> 2) + 4 * hi;
      out[(size_t)grow * 512 + c] = acc[tt][r] + bc;
    }
  }
}

// ---------------------------------------------------------------------------
extern "C" void kernel_launch(void* const* d_in, const int* in_sizes, int n_in,
                              void* d_out, int out_size, void* d_ws, size_t ws_size,
                              hipStream_t stream) {
  const float* query = (const float*)d_in[0];
  const float* key_  = (const float*)d_in[1];
  const float* value = (const float*)d_in[2];
  const int*   mask  = (const int*)d_in[3];
  const float* Wq = (const float*)d_in[4];
  const float* bq = (const float*)d_in[5];
  const float* Wk = (const float*)d_in[6];
  const float* bk = (const float*)d_in[7];
  const float* Wv = (const float*)d_in[8];
  const float* bv = (const float*)d_in[9];
  const float* Wx = (const float*)d_in[10];
  const float* bx = (const float*)d_in[11];

  const int M = NB * S_LEN;                  // 8192
  float* out_x = (float*)d_out;              // [4,2048,512]
  float* out_p = out_x + (size_t)M * 512;    // [4,8,2048,2048]

  unsigned short* wqT  = (unsigned short*)d_ws;             // 96*512
  unsigned short* wkT  = wqT + 49152;                       // 96*512
  unsigned short* wvT  = wkT + 49152;                       // 256*512
  unsigned short* wxT  = wvT + 131072;                      // 512*256
  unsigned short* q_bf = wxT + 131072;                      // 8192*128
  unsigned short* k_bf = q_bf + (size_t)M * 128;            // 8192*128
  unsigned short* vT_bf = k_bf + (size_t)M * 128;           // 4*256*2048
  unsigned short* x_bf = vT_bf + (size_t)NB * 256 * S_LEN;  // 8192*256

  // 1/sqrt(12) * log2(e): scores come out of the MFMA in log2 units, so
  // softmax needs only raw v_exp_f32 (exp2), no per-element multiply.
  const float qscale = 1.4426950408889634f / sqrtf(12.0f);

  transpose_w<<<1408, 256, 0, stream>>>(Wq, Wk, Wv, Wx, wqT, wkT, wvT, wxT);

  proj_qkv<<<512, 256, 0, stream>>>(
      query, key_, value, mask, wqT, wkT, wvT, bq, bk, bv,
      q_bf, k_bf, vT_bf, qscale);

  attn_mfma<<<dim3(S_LEN / 32, NB * NH), 256, 0, stream>>>(
      q_bf, k_bf, vT_bf, out_p, x_bf);

  out_proj<<<256, 256, 0, stream>>>(x_bf, wxT, bx, out_x);
}